// Round 6
// baseline (445.707 us; speedup 1.0000x reference)
//
#include <hip/hip_runtime.h>
#include <hip/hip_bf16.h>

// Problem constants (fixed by reference)
#define N_NODES 20000
#define NUM_DRUGS 2048
#define NUM_DPI 200000
#define E2 400000          // 2*NUM_DPI directed edges
#define CDIM 256           // IN_C == EMB == 256
#define HID 512
#define N_CL 8
#define BATCH 16384

#define STRD 32            // drug/cl counter padding (ints) = 1 line per counter
#define STRP 16            // protein counter padding

typedef __attribute__((ext_vector_type(8))) short short8;   // 8 bf16 (MFMA A/B frag)
typedef __attribute__((ext_vector_type(4))) float floatx4;  // MFMA C/D frag

__device__ inline unsigned short f2bf(float f) {
    unsigned u = __float_as_uint(f);
    u += 0x7fff + ((u >> 16) & 1);   // RNE
    return (unsigned short)(u >> 16);
}
__device__ inline float bf2f(unsigned short h) {
    return __uint_as_float((unsigned)h << 16);
}
__device__ inline void split2(float v, unsigned short& h, unsigned short& l) {
    h = f2bf(v);
    l = f2bf(v - bf2f(h));
}
__device__ inline void gload16(const void* g, void* l) {
    __builtin_amdgcn_global_load_lds(
        (const __attribute__((address_space(1))) void*)g,
        (__attribute__((address_space(3))) void*)l, 16, 0, 0);
}
__device__ inline float4 f4fma(float4 v, float s, float4 a) {
    a.x = fmaf(v.x, s, a.x); a.y = fmaf(v.y, s, a.y);
    a.z = fmaf(v.z, s, a.z); a.w = fmaf(v.w, s, a.w);
    return a;
}

// ---------------------------------------------------------------------------
__global__ void zero_counts(int* cnt_d, int* cur_d, int* cnt_p, int* cur_p,
                            int* clcnt, int* curcl) {
    int i = blockIdx.x * blockDim.x + threadIdx.x;
    if (i < N_NODES) { cnt_p[i * STRP] = 0; cur_p[i * STRP] = 0; }
    if (i < NUM_DRUGS) { cnt_d[i * STRD] = 0; cur_d[i * STRD] = 0; }
    if (i < N_CL) { clcnt[i * STRD] = 0; curcl[i * STRD] = 0; }
}

// count DPI pairs into padded per-drug / per-protein histograms
__global__ void count_dpi(const int* __restrict__ ei, int* cnt_d, int* cnt_p) {
    int e = blockIdx.x * blockDim.x + threadIdx.x;
    if (e >= NUM_DPI) return;
    atomicAdd(&cnt_d[ei[e] * STRD], 1);          // drug id of pair e
    atomicAdd(&cnt_p[ei[E2 + e] * STRP], 1);     // protein id of pair e
}

// cell-line histogram via block-local LDS bins (16K atomics -> 512)
__global__ void count_cl(const int* __restrict__ ecl, int* clcnt) {
    __shared__ int lh[N_CL];
    int t = threadIdx.x;
    int r = blockIdx.x * 256 + t;
    if (t < N_CL) lh[t] = 0;
    __syncthreads();
    atomicAdd(&lh[ecl[r]], 1);
    __syncthreads();
    if (t < N_CL && lh[t] > 0) atomicAdd(&clcnt[t * STRD], lh[t]);
}

// generic strided single-block exclusive scan
__device__ void scan_dev(const int* counts, int stride, int* ptr, int n) {
    __shared__ int sums[1024];
    int t = threadIdx.x;
    int per = (n + 1023) / 1024;
    int start = t * per;
    int end = start + per; if (end > n) end = n;
    int s = 0;
    for (int i = start; i < end; i++) s += counts[i * stride];
    sums[t] = s;
    __syncthreads();
    for (int off = 1; off < 1024; off <<= 1) {
        int v = (t >= off) ? sums[t - off] : 0;
        __syncthreads();
        sums[t] += v;
        __syncthreads();
    }
    int base = (t == 0) ? 0 : sums[t - 1];
    for (int i = start; i < end; i++) {
        ptr[i] = base;
        base += counts[i * stride];
    }
    if (t == 1023) ptr[n] = sums[1023];
}

__global__ void scan3(const int* cnt_d, const int* cnt_p, const int* clcnt,
                      int* drug_ptr, int* prot_ptr, int* cloff) {
    if (blockIdx.x == 0) scan_dev(cnt_d, STRD, drug_ptr, NUM_DRUGS);
    else if (blockIdx.x == 1) scan_dev(cnt_p, STRP, prot_ptr, N_NODES);
    else scan_dev(clcnt, STRD, cloff, N_CL);
}

// fill both adjacency lists from DPI pairs; padded counters kill line ping-pong
__global__ void fill_dpi(const int* __restrict__ ei,
                         const int* __restrict__ drug_ptr, int* cur_d, int* adj_drug,
                         const int* __restrict__ prot_ptr, int* cur_p, int* adj_prot,
                         float* __restrict__ dinv) {
    int e = blockIdx.x * blockDim.x + threadIdx.x;
    if (e < NUM_DPI) {
        int d = ei[e];
        int p = ei[E2 + e];
        int posd = drug_ptr[d] + atomicAdd(&cur_d[d * STRD], 1);
        int posp = prot_ptr[p] + atomicAdd(&cur_p[p * STRP], 1);
        adj_drug[posd] = p;
        adj_prot[posp] = d;
    }
    if (e < N_NODES) {
        int deg = (e < NUM_DRUGS) ? (drug_ptr[e + 1] - drug_ptr[e])
                                  : (prot_ptr[e + 1] - prot_ptr[e]);
        dinv[e] = rsqrtf((float)(deg + 1));
    }
}

// perm (rows grouped by cell line) via block-level two-phase allocation
__global__ void fill_perm(const int* __restrict__ ecl, int* curcl,
                          const int* __restrict__ cloff, int* __restrict__ perm) {
    __shared__ int lh[N_CL];
    __shared__ int gbase[N_CL];
    int t = threadIdx.x;
    int r = blockIdx.x * 256 + t;
    if (t < N_CL) lh[t] = 0;
    __syncthreads();
    int c = ecl[r];
    int lrank = atomicAdd(&lh[c], 1);
    __syncthreads();
    if (t < N_CL) gbase[t] = (lh[t] > 0) ? atomicAdd(&curcl[t * STRD], lh[t]) : 0;
    __syncthreads();
    perm[cloff[c] + gbase[c] + lrank] = r;
}

// ---------------------------------------------------------------------------
// fp32 -> (hi,lo) bf16 split, elementwise (coalesced)
__global__ void split_mat(const float* __restrict__ A, unsigned short* __restrict__ hi,
                          unsigned short* __restrict__ lo, int total) {
    int i = blockIdx.x * blockDim.x + threadIdx.x;
    if (i >= total) return;
    unsigned short h, l;
    split2(A[i], h, l);
    hi[i] = h; lo[i] = l;
}

// LDS-tiled transpose+split: W [m][K][N] fp32 -> [m][N][K] split bf16, coalesced
__global__ __launch_bounds__(256) void transpose_split64(const float* __restrict__ W,
                                                         unsigned short* __restrict__ hi,
                                                         unsigned short* __restrict__ lo,
                                                         int K, int N) {
    __shared__ float ld[64 * 65];
    int m = blockIdx.z;
    int k0 = blockIdx.x * 64, n0 = blockIdx.y * 64;
    const float* Wm = W + (size_t)m * K * N;
    int tx = threadIdx.x & 63, ty = threadIdx.x >> 6;
#pragma unroll
    for (int rr = 0; rr < 16; rr++) {
        int kl = rr * 4 + ty;
        ld[tx * 65 + kl] = Wm[(size_t)(k0 + kl) * N + n0 + tx];
    }
    __syncthreads();
    size_t obase = (size_t)m * N * K;
#pragma unroll
    for (int rr = 0; rr < 16; rr++) {
        int nl = rr * 4 + ty;
        float v = ld[nl * 65 + tx];
        unsigned short h, l;
        split2(v, h, l);
        size_t o = obase + (size_t)(n0 + nl) * K + k0 + tx;
        hi[o] = h;
        lo[o] = l;
    }
}

// ---------------------------------------------------------------------------
// split-bf16 MFMA GEMM: C[M,N] = A[M,K] @ B[K,N], B passed as B^T ([N][K]).
// Chunk-major LDS layout: slot(row, kchunk) = kchunk*128 + row (16B slots)
// -> quad frag reads are contiguous 256B, conflict-free.
__global__ __launch_bounds__(256) void gemm_mfma(
        const unsigned short* __restrict__ Ahi, const unsigned short* __restrict__ Alo,
        const unsigned short* __restrict__ BThi, const unsigned short* __restrict__ BTlo,
        float* __restrict__ C, int M, int K, int N) {
    __shared__ unsigned short sAh[4096], sAl[4096], sBh[4096], sBl[4096];
    int t = threadIdx.x;
    int wv = t >> 6, lane = t & 63, quad = lane >> 4, l15 = lane & 15;
    int m0 = blockIdx.x * 128, n0 = blockIdx.y * 128;
    int m0w = (wv >> 1) * 64, n0w = (wv & 1) * 64;
    floatx4 zero = {0.f, 0.f, 0.f, 0.f};
    floatx4 acc[4][4];
#pragma unroll
    for (int i = 0; i < 4; i++)
#pragma unroll
        for (int j = 0; j < 4; j++) acc[i][j] = zero;

    for (int kk = 0; kk < K; kk += 32) {
#pragma unroll
        for (int c = 0; c < 2; c++) {
            int s = t + c * 256;                 // slot in [0,512)
            int row = s & 127, chunk = s >> 7;
            int arow = m0 + row; if (arow > M - 1) arow = M - 1;
            int brow = n0 + row; if (brow > N - 1) brow = N - 1;
            size_t aoff = (size_t)arow * K + kk + chunk * 8;
            size_t boff = (size_t)brow * K + kk + chunk * 8;
            gload16(Ahi + aoff, &sAh[s * 8]);
            gload16(Alo + aoff, &sAl[s * 8]);
            gload16(BThi + boff, &sBh[s * 8]);
            gload16(BTlo + boff, &sBl[s * 8]);
        }
        __syncthreads();
        short8 ah[4], al[4], bh[4], bl[4];
#pragma unroll
        for (int i = 0; i < 4; i++) {
            int sl = quad * 128 + m0w + i * 16 + l15;
            ah[i] = *(const short8*)&sAh[sl * 8];
            al[i] = *(const short8*)&sAl[sl * 8];
        }
#pragma unroll
        for (int j = 0; j < 4; j++) {
            int sl = quad * 128 + n0w + j * 16 + l15;
            bh[j] = *(const short8*)&sBh[sl * 8];
            bl[j] = *(const short8*)&sBl[sl * 8];
        }
#pragma unroll
        for (int i = 0; i < 4; i++)
#pragma unroll
            for (int j = 0; j < 4; j++) {
                acc[i][j] = __builtin_amdgcn_mfma_f32_16x16x32_bf16(ah[i], bh[j], acc[i][j], 0, 0, 0);
                acc[i][j] = __builtin_amdgcn_mfma_f32_16x16x32_bf16(ah[i], bl[j], acc[i][j], 0, 0, 0);
                acc[i][j] = __builtin_amdgcn_mfma_f32_16x16x32_bf16(al[i], bh[j], acc[i][j], 0, 0, 0);
            }
        __syncthreads();
    }
#pragma unroll
    for (int i = 0; i < 4; i++) {
        int gr = m0 + m0w + i * 16 + quad * 4;
#pragma unroll
        for (int r = 0; r < 4; r++) {
            if (gr + r < M) {
#pragma unroll
                for (int j = 0; j < 4; j++)
                    C[(size_t)(gr + r) * N + n0 + n0w + j * 16 + l15] = acc[i][j][r];
            }
        }
    }
}

// ---------------------------------------------------------------------------
// GCN aggregate; 4-way unrolled neighbor loop for memory-level parallelism
__global__ __launch_bounds__(256) void aggregate_k(const float* __restrict__ tmp,
                                                   const int* __restrict__ drug_ptr,
                                                   const int* __restrict__ adj_drug,
                                                   const int* __restrict__ prot_ptr,
                                                   const int* __restrict__ adj_prot,
                                                   const float* __restrict__ dinv,
                                                   const float* __restrict__ bias,
                                                   float* __restrict__ outf,
                                                   unsigned short* __restrict__ outhi,
                                                   unsigned short* __restrict__ outlo) {
    int wave = (blockIdx.x * blockDim.x + threadIdx.x) >> 6;
    int lane = threadIdx.x & 63;
    if (wave >= N_NODES) return;
    int i = wave;
    const int* adj;
    int s, e;
    if (i < NUM_DRUGS) { s = drug_ptr[i]; e = drug_ptr[i + 1]; adj = adj_drug; }
    else               { s = prot_ptr[i]; e = prot_ptr[i + 1]; adj = adj_prot; }
    float di = dinv[i];
    float4 a0 = make_float4(0.f, 0.f, 0.f, 0.f);
    float4 a1 = a0, a2 = a0, a3 = a0;
    int idx = s;
    for (; idx + 4 <= e; idx += 4) {
        int j0 = adj[idx + 0], j1 = adj[idx + 1], j2 = adj[idx + 2], j3 = adj[idx + 3];
        float d0 = dinv[j0], d1 = dinv[j1], d2 = dinv[j2], d3 = dinv[j3];
        float4 v0 = ((const float4*)(tmp + (size_t)j0 * CDIM))[lane];
        float4 v1 = ((const float4*)(tmp + (size_t)j1 * CDIM))[lane];
        float4 v2 = ((const float4*)(tmp + (size_t)j2 * CDIM))[lane];
        float4 v3 = ((const float4*)(tmp + (size_t)j3 * CDIM))[lane];
        a0 = f4fma(v0, d0, a0);
        a1 = f4fma(v1, d1, a1);
        a2 = f4fma(v2, d2, a2);
        a3 = f4fma(v3, d3, a3);
    }
    for (; idx < e; idx++) {
        int j = adj[idx];
        float dj = dinv[j];
        float4 v = ((const float4*)(tmp + (size_t)j * CDIM))[lane];
        a0 = f4fma(v, dj, a0);
    }
    float4 self = ((const float4*)(tmp + (size_t)i * CDIM))[lane];
    float4 acc;
    acc.x = (a0.x + a1.x) + (a2.x + a3.x) + self.x * di;
    acc.y = (a0.y + a1.y) + (a2.y + a3.y) + self.y * di;
    acc.z = (a0.z + a1.z) + (a2.z + a3.z) + self.z * di;
    acc.w = (a0.w + a1.w) + (a2.w + a3.w) + self.w * di;
    float4 bv = ((const float4*)bias)[lane];
    float4 r;
    r.x = fmaxf(fmaf(acc.x, di, bv.x), 0.f);
    r.y = fmaxf(fmaf(acc.y, di, bv.y), 0.f);
    r.z = fmaxf(fmaf(acc.z, di, bv.z), 0.f);
    r.w = fmaxf(fmaf(acc.w, di, bv.w), 0.f);
    if (outhi) {
        ushort4 h, l;
        split2(r.x, h.x, l.x); split2(r.y, h.y, l.y);
        split2(r.z, h.z, l.z); split2(r.w, h.w, l.w);
        *(ushort4*)&outhi[(size_t)i * CDIM + lane * 4] = h;
        *(ushort4*)&outlo[(size_t)i * CDIM + lane * 4] = l;
    } else {
        ((float4*)(outf + (size_t)i * CDIM))[lane] = r;
    }
}

// scatter-mean pool -> split-bf16 graph embeddings; 4-way unrolled
__global__ __launch_bounds__(256) void pool_drugs(const float* __restrict__ h2,
                                                  unsigned short* __restrict__ Ghi,
                                                  unsigned short* __restrict__ Glo,
                                                  const int* __restrict__ drug_ptr,
                                                  const int* __restrict__ adj_drug) {
    int wave = (blockIdx.x * blockDim.x + threadIdx.x) >> 6;
    int lane = threadIdx.x & 63;
    if (wave >= NUM_DRUGS) return;
    int d = wave;
    int s = drug_ptr[d], e = drug_ptr[d + 1];
    float4 a0 = make_float4(0.f, 0.f, 0.f, 0.f);
    float4 a1 = a0, a2 = a0, a3 = a0;
    int idx = s;
    for (; idx + 4 <= e; idx += 4) {
        int j0 = adj_drug[idx + 0], j1 = adj_drug[idx + 1];
        int j2 = adj_drug[idx + 2], j3 = adj_drug[idx + 3];
        float4 v0 = ((const float4*)(h2 + (size_t)j0 * CDIM))[lane];
        float4 v1 = ((const float4*)(h2 + (size_t)j1 * CDIM))[lane];
        float4 v2 = ((const float4*)(h2 + (size_t)j2 * CDIM))[lane];
        float4 v3 = ((const float4*)(h2 + (size_t)j3 * CDIM))[lane];
        a0.x += v0.x; a0.y += v0.y; a0.z += v0.z; a0.w += v0.w;
        a1.x += v1.x; a1.y += v1.y; a1.z += v1.z; a1.w += v1.w;
        a2.x += v2.x; a2.y += v2.y; a2.z += v2.z; a2.w += v2.w;
        a3.x += v3.x; a3.y += v3.y; a3.z += v3.z; a3.w += v3.w;
    }
    for (; idx < e; idx++) {
        int j = adj_drug[idx];
        float4 v = ((const float4*)(h2 + (size_t)j * CDIM))[lane];
        a0.x += v.x; a0.y += v.y; a0.z += v.z; a0.w += v.w;
    }
    float4 acc;
    acc.x = (a0.x + a1.x) + (a2.x + a3.x);
    acc.y = (a0.y + a1.y) + (a2.y + a3.y);
    acc.z = (a0.z + a1.z) + (a2.z + a3.z);
    acc.w = (a0.w + a1.w) + (a2.w + a3.w);
    int cnt = e - s;
    float sc = 1.f / (float)(cnt > 1 ? cnt : 1);
    acc.x *= sc; acc.y *= sc; acc.z *= sc; acc.w *= sc;
    ushort4 h, l;
    split2(acc.x, h.x, l.x); split2(acc.y, h.y, l.y);
    split2(acc.z, h.z, l.z); split2(acc.w, h.w, l.w);
    *(ushort4*)&Ghi[(size_t)d * CDIM + lane * 4] = h;
    *(ushort4*)&Glo[(size_t)d * CDIM + lane * 4] = l;
}

__global__ void out_init(float* __restrict__ outp, const int* __restrict__ ecl,
                         const float* __restrict__ b2) {
    int i = blockIdx.x * blockDim.x + threadIdx.x;
    if (i < BATCH) outp[i] = b2[ecl[i]];
}

// ---------------------------------------------------------------------------
// grouped MoE MLP via split-bf16 MFMA; 128x128 tile (best measured), chunk-major
// conflict-free LDS, XCD-pinned experts (expert = blockIdx.x % 8 so each XCD's
// L2 holds exactly one expert's W1T + G); fused relu+b1 and [512,1] layer-2.
#define MLP_RT 24           // row-tile slots per expert (24*128 = 3072 rows max)
__global__ __launch_bounds__(256) void mlp_mfma(
        const unsigned short* __restrict__ Ghi, const unsigned short* __restrict__ Glo,
        const unsigned short* __restrict__ W1Thi, const unsigned short* __restrict__ W1Tlo,
        const float* __restrict__ b1, const float* __restrict__ W2,
        const int* __restrict__ ddb, const int* __restrict__ perm,
        const int* __restrict__ cloff, float* __restrict__ outp) {
    int bid = blockIdx.x;
    int e = bid & 7;                 // XCD-pinned expert
    int rr_ = bid >> 3;
    int ct = rr_ & 3;
    int rt = rr_ >> 2;               // 0..MLP_RT-1
    int lo_ = cloff[e], hi_ = cloff[e + 1];
    int base = lo_ + rt * 128;
    if (base >= hi_) return;
    __shared__ unsigned short sAh[4096], sAl[4096], sBh[4096], sBl[4096];
    __shared__ int rid[128], g0s[128], g1s[128];
    int t = threadIdx.x;
    if (t < 128) {
        int idx = base + t;
        if (idx < hi_) {
            int r = perm[idx];
            rid[t] = r;
            g0s[t] = ddb[r] * CDIM;
            g1s[t] = ddb[BATCH + r] * CDIM;
        } else { rid[t] = -1; g0s[t] = 0; g1s[t] = 0; }
    }
    __syncthreads();
    int wv = t >> 6, lane = t & 63, quad = lane >> 4, l15 = lane & 15;
    int n0 = ct * 128;
    int m0w = (wv >> 1) * 64, n0w = (wv & 1) * 64;
    const unsigned short* W1eh = W1Thi + (size_t)e * HID * HID;
    const unsigned short* W1el = W1Tlo + (size_t)e * HID * HID;
    floatx4 zero = {0.f, 0.f, 0.f, 0.f};
    floatx4 acc[4][4];
#pragma unroll
    for (int i = 0; i < 4; i++)
#pragma unroll
        for (int j = 0; j < 4; j++) acc[i][j] = zero;

    for (int kk = 0; kk < 2 * CDIM; kk += 32) {
        const int* gsel = (kk < CDIM) ? g0s : g1s;
        int kbase = kk & (CDIM - 1);
#pragma unroll
        for (int c = 0; c < 2; c++) {
            int s = t + c * 256;                 // slot in [0,512)
            int row = s & 127, chunk = s >> 7;
            size_t aoff = (size_t)gsel[row] + kbase + chunk * 8;
            size_t boff = (size_t)(n0 + row) * HID + kk + chunk * 8;
            gload16(Ghi + aoff, &sAh[s * 8]);
            gload16(Glo + aoff, &sAl[s * 8]);
            gload16(W1eh + boff, &sBh[s * 8]);
            gload16(W1el + boff, &sBl[s * 8]);
        }
        __syncthreads();
        short8 ah[4], al[4], bh[4], bl[4];
#pragma unroll
        for (int i = 0; i < 4; i++) {
            int sl = quad * 128 + m0w + i * 16 + l15;
            ah[i] = *(const short8*)&sAh[sl * 8];
            al[i] = *(const short8*)&sAl[sl * 8];
        }
#pragma unroll
        for (int j = 0; j < 4; j++) {
            int sl = quad * 128 + n0w + j * 16 + l15;
            bh[j] = *(const short8*)&sBh[sl * 8];
            bl[j] = *(const short8*)&sBl[sl * 8];
        }
#pragma unroll
        for (int i = 0; i < 4; i++)
#pragma unroll
            for (int j = 0; j < 4; j++) {
                acc[i][j] = __builtin_amdgcn_mfma_f32_16x16x32_bf16(ah[i], bh[j], acc[i][j], 0, 0, 0);
                acc[i][j] = __builtin_amdgcn_mfma_f32_16x16x32_bf16(ah[i], bl[j], acc[i][j], 0, 0, 0);
                acc[i][j] = __builtin_amdgcn_mfma_f32_16x16x32_bf16(al[i], bh[j], acc[i][j], 0, 0, 0);
            }
        __syncthreads();
    }
    const float* b1e = b1 + (size_t)e * HID;
    const float* W2e = W2 + (size_t)e * HID;
#pragma unroll
    for (int i = 0; i < 4; i++) {
#pragma unroll
        for (int r = 0; r < 4; r++) {
            float s = 0.f;
#pragma unroll
            for (int j = 0; j < 4; j++) {
                int col = n0 + n0w + j * 16 + l15;
                float h = fmaxf(acc[i][j][r] + b1e[col], 0.f);
                s = fmaf(h, W2e[col], s);
            }
            s += __shfl_xor(s, 1, 16);
            s += __shfl_xor(s, 2, 16);
            s += __shfl_xor(s, 4, 16);
            s += __shfl_xor(s, 8, 16);
            if (l15 == 0) {
                int rowl = m0w + i * 16 + quad * 4 + r;
                int rr2 = rid[rowl];
                if (rr2 >= 0) atomicAdd(&outp[rr2], s);
            }
        }
    }
}

// ---------------------------------------------------------------------------
extern "C" void kernel_launch(void* const* d_in, const int* in_sizes, int n_in,
                              void* d_out, int out_size, void* d_ws, size_t ws_size,
                              hipStream_t stream) {
    const float* x   = (const float*)d_in[0];
    const int* ei    = (const int*)d_in[1];
    const int* ddb   = (const int*)d_in[2];
    const int* ecl   = (const int*)d_in[3];
    const float* Wg1 = (const float*)d_in[5];
    const float* bg1 = (const float*)d_in[6];
    const float* Wg2 = (const float*)d_in[7];
    const float* bg2 = (const float*)d_in[8];
    const float* W1  = (const float*)d_in[9];
    const float* b1  = (const float*)d_in[10];
    const float* W2  = (const float*)d_in[11];
    const float* b2  = (const float*)d_in[12];
    float* outp = (float*)d_out;

    char* p = (char*)d_ws;
    auto alloc = [&](size_t bytes) {
        char* r = p;
        p += (bytes + 255) & ~size_t(255);
        return (void*)r;
    };
    const size_t NC = (size_t)N_NODES * CDIM;
    float* tmp            = (float*)alloc(sizeof(float) * NC);
    unsigned short* h1hi  = (unsigned short*)alloc(2 * NC);
    unsigned short* h1lo  = (unsigned short*)alloc(2 * NC);
    char* xh2_blk         = (char*)alloc(4 * NC);                 // xhi+xlo, later h2
    unsigned short* xhi   = (unsigned short*)xh2_blk;
    unsigned short* xlo   = (unsigned short*)(xh2_blk + 2 * NC);
    float* h2             = (float*)xh2_blk;
    unsigned short* Ghi   = (unsigned short*)alloc(2 * NUM_DRUGS * CDIM);
    unsigned short* Glo   = (unsigned short*)alloc(2 * NUM_DRUGS * CDIM);
    unsigned short* wg1Th = (unsigned short*)alloc(2 * CDIM * CDIM);
    unsigned short* wg1Tl = (unsigned short*)alloc(2 * CDIM * CDIM);
    unsigned short* wg2Th = (unsigned short*)alloc(2 * CDIM * CDIM);
    unsigned short* wg2Tl = (unsigned short*)alloc(2 * CDIM * CDIM);
    unsigned short* W1Th  = (unsigned short*)alloc(2 * (size_t)N_CL * HID * HID);
    unsigned short* W1Tl  = (unsigned short*)alloc(2 * (size_t)N_CL * HID * HID);
    float* dinv    = (float*)alloc(sizeof(float) * N_NODES);
    int* cnt_d     = (int*)alloc(sizeof(int) * NUM_DRUGS * STRD);
    int* cur_d     = (int*)alloc(sizeof(int) * NUM_DRUGS * STRD);
    int* cnt_p     = (int*)alloc(sizeof(int) * N_NODES * STRP);
    int* cur_p     = (int*)alloc(sizeof(int) * N_NODES * STRP);
    int* drug_ptr  = (int*)alloc(sizeof(int) * (NUM_DRUGS + 1));
    int* prot_ptr  = (int*)alloc(sizeof(int) * (N_NODES + 1));
    int* adj_drug  = (int*)alloc(sizeof(int) * NUM_DPI);
    int* adj_prot  = (int*)alloc(sizeof(int) * NUM_DPI);
    int* clcnt     = (int*)alloc(sizeof(int) * N_CL * STRD);
    int* curcl     = (int*)alloc(sizeof(int) * N_CL * STRD);
    int* cloff     = (int*)alloc(sizeof(int) * (N_CL + 1));
    int* perm      = (int*)alloc(sizeof(int) * BATCH);

    // graph prep
    zero_counts<<<(N_NODES + 255) / 256, 256, 0, stream>>>(cnt_d, cur_d, cnt_p, cur_p,
                                                           clcnt, curcl);
    count_dpi<<<(NUM_DPI + 255) / 256, 256, 0, stream>>>(ei, cnt_d, cnt_p);
    count_cl<<<BATCH / 256, 256, 0, stream>>>(ecl, clcnt);
    scan3<<<3, 1024, 0, stream>>>(cnt_d, cnt_p, clcnt, drug_ptr, prot_ptr, cloff);
    fill_dpi<<<(NUM_DPI + 255) / 256, 256, 0, stream>>>(ei, drug_ptr, cur_d, adj_drug,
                                                        prot_ptr, cur_p, adj_prot, dinv);
    fill_perm<<<BATCH / 256, 256, 0, stream>>>(ecl, curcl, cloff, perm);
    // weight/activation splits (coalesced)
    split_mat<<<((int)NC + 255) / 256, 256, 0, stream>>>(x, xhi, xlo, (int)NC);
    transpose_split64<<<dim3(CDIM / 64, CDIM / 64, 1), 256, 0, stream>>>(
        Wg1, wg1Th, wg1Tl, CDIM, CDIM);
    transpose_split64<<<dim3(CDIM / 64, CDIM / 64, 1), 256, 0, stream>>>(
        Wg2, wg2Th, wg2Tl, CDIM, CDIM);
    transpose_split64<<<dim3(HID / 64, HID / 64, N_CL), 256, 0, stream>>>(
        W1, W1Th, W1Tl, HID, HID);
    // GCN layer 1
    gemm_mfma<<<dim3((N_NODES + 127) / 128, CDIM / 128), 256, 0, stream>>>(
        xhi, xlo, wg1Th, wg1Tl, tmp, N_NODES, CDIM, CDIM);
    aggregate_k<<<(N_NODES * 64 + 255) / 256, 256, 0, stream>>>(
        tmp, drug_ptr, adj_drug, prot_ptr, adj_prot, dinv, bg1, nullptr, h1hi, h1lo);
    // GCN layer 2
    gemm_mfma<<<dim3((N_NODES + 127) / 128, CDIM / 128), 256, 0, stream>>>(
        h1hi, h1lo, wg2Th, wg2Tl, tmp, N_NODES, CDIM, CDIM);
    aggregate_k<<<(N_NODES * 64 + 255) / 256, 256, 0, stream>>>(
        tmp, drug_ptr, adj_drug, prot_ptr, adj_prot, dinv, bg2, h2, nullptr, nullptr);
    // pool -> split graph embeddings
    pool_drugs<<<(NUM_DRUGS * 64 + 255) / 256, 256, 0, stream>>>(h2, Ghi, Glo,
                                                                 drug_ptr, adj_drug);
    // MoE MLP (1-D grid, expert = bid % 8 -> XCD-pinned)
    out_init<<<(BATCH + 255) / 256, 256, 0, stream>>>(outp, ecl, b2);
    mlp_mfma<<<8 * 4 * MLP_RT, 256, 0, stream>>>(
        Ghi, Glo, W1Th, W1Tl, b1, W2, ddb, perm, cloff, outp);
}

// Round 7
// 404.643 us; speedup vs baseline: 1.1015x; 1.1015x over previous
//
#include <hip/hip_runtime.h>
#include <hip/hip_bf16.h>

// Problem constants (fixed by reference)
#define N_NODES 20000
#define NUM_DRUGS 2048
#define NUM_DPI 200000
#define E2 400000          // 2*NUM_DPI directed edges
#define CDIM 256           // IN_C == EMB == 256
#define HID 512
#define N_CL 8
#define BATCH 16384

#define STRD 32            // drug/cl counter padding (ints) = 1 line per counter
#define STRP 16            // protein counter padding

typedef __attribute__((ext_vector_type(8))) short short8;   // 8 bf16 (MFMA A/B frag)
typedef __attribute__((ext_vector_type(4))) float floatx4;  // MFMA C/D frag

__device__ inline unsigned short f2bf(float f) {
    unsigned u = __float_as_uint(f);
    u += 0x7fff + ((u >> 16) & 1);   // RNE
    return (unsigned short)(u >> 16);
}
__device__ inline float bf2f(unsigned short h) {
    return __uint_as_float((unsigned)h << 16);
}
__device__ inline void split2(float v, unsigned short& h, unsigned short& l) {
    h = f2bf(v);
    l = f2bf(v - bf2f(h));
}
__device__ inline void gload16(const void* g, void* l) {
    __builtin_amdgcn_global_load_lds(
        (const __attribute__((address_space(1))) void*)g,
        (__attribute__((address_space(3))) void*)l, 16, 0, 0);
}
__device__ inline float4 f4fma(float4 v, float s, float4 a) {
    a.x = fmaf(v.x, s, a.x); a.y = fmaf(v.y, s, a.y);
    a.z = fmaf(v.z, s, a.z); a.w = fmaf(v.w, s, a.w);
    return a;
}

// ---------------------------------------------------------------------------
__global__ void zero_counts(int* cnt_d, int* cur_d, int* cnt_p, int* cur_p,
                            int* clcnt, int* curcl) {
    int i = blockIdx.x * blockDim.x + threadIdx.x;
    if (i < N_NODES) { cnt_p[i * STRP] = 0; cur_p[i * STRP] = 0; }
    if (i < NUM_DRUGS) { cnt_d[i * STRD] = 0; cur_d[i * STRD] = 0; }
    if (i < N_CL) { clcnt[i * STRD] = 0; curcl[i * STRD] = 0; }
}

// count DPI pairs into padded per-drug / per-protein histograms
__global__ void count_dpi(const int* __restrict__ ei, int* cnt_d, int* cnt_p) {
    int e = blockIdx.x * blockDim.x + threadIdx.x;
    if (e >= NUM_DPI) return;
    atomicAdd(&cnt_d[ei[e] * STRD], 1);          // drug id of pair e
    atomicAdd(&cnt_p[ei[E2 + e] * STRP], 1);     // protein id of pair e
}

// cell-line histogram via block-local LDS bins (16K atomics -> 512)
__global__ void count_cl(const int* __restrict__ ecl, int* clcnt) {
    __shared__ int lh[N_CL];
    int t = threadIdx.x;
    int r = blockIdx.x * 256 + t;
    if (t < N_CL) lh[t] = 0;
    __syncthreads();
    atomicAdd(&lh[ecl[r]], 1);
    __syncthreads();
    if (t < N_CL && lh[t] > 0) atomicAdd(&clcnt[t * STRD], lh[t]);
}

// generic strided single-block exclusive scan
__device__ void scan_dev(const int* counts, int stride, int* ptr, int n) {
    __shared__ int sums[1024];
    int t = threadIdx.x;
    int per = (n + 1023) / 1024;
    int start = t * per;
    int end = start + per; if (end > n) end = n;
    int s = 0;
    for (int i = start; i < end; i++) s += counts[i * stride];
    sums[t] = s;
    __syncthreads();
    for (int off = 1; off < 1024; off <<= 1) {
        int v = (t >= off) ? sums[t - off] : 0;
        __syncthreads();
        sums[t] += v;
        __syncthreads();
    }
    int base = (t == 0) ? 0 : sums[t - 1];
    for (int i = start; i < end; i++) {
        ptr[i] = base;
        base += counts[i * stride];
    }
    if (t == 1023) ptr[n] = sums[1023];
}

__global__ void scan3(const int* cnt_d, const int* cnt_p, const int* clcnt,
                      int* drug_ptr, int* prot_ptr, int* cloff) {
    if (blockIdx.x == 0) scan_dev(cnt_d, STRD, drug_ptr, NUM_DRUGS);
    else if (blockIdx.x == 1) scan_dev(cnt_p, STRP, prot_ptr, N_NODES);
    else scan_dev(clcnt, STRD, cloff, N_CL);
}

// fill both adjacency lists from DPI pairs; padded counters kill line ping-pong
__global__ void fill_dpi(const int* __restrict__ ei,
                         const int* __restrict__ drug_ptr, int* cur_d, int* adj_drug,
                         const int* __restrict__ prot_ptr, int* cur_p, int* adj_prot,
                         float* __restrict__ dinv) {
    int e = blockIdx.x * blockDim.x + threadIdx.x;
    if (e < NUM_DPI) {
        int d = ei[e];
        int p = ei[E2 + e];
        int posd = drug_ptr[d] + atomicAdd(&cur_d[d * STRD], 1);
        int posp = prot_ptr[p] + atomicAdd(&cur_p[p * STRP], 1);
        adj_drug[posd] = p;
        adj_prot[posp] = d;
    }
    if (e < N_NODES) {
        int deg = (e < NUM_DRUGS) ? (drug_ptr[e + 1] - drug_ptr[e])
                                  : (prot_ptr[e + 1] - prot_ptr[e]);
        dinv[e] = rsqrtf((float)(deg + 1));
    }
}

// perm (rows grouped by cell line) via block-level two-phase allocation
__global__ void fill_perm(const int* __restrict__ ecl, int* curcl,
                          const int* __restrict__ cloff, int* __restrict__ perm) {
    __shared__ int lh[N_CL];
    __shared__ int gbase[N_CL];
    int t = threadIdx.x;
    int r = blockIdx.x * 256 + t;
    if (t < N_CL) lh[t] = 0;
    __syncthreads();
    int c = ecl[r];
    int lrank = atomicAdd(&lh[c], 1);
    __syncthreads();
    if (t < N_CL) gbase[t] = (lh[t] > 0) ? atomicAdd(&curcl[t * STRD], lh[t]) : 0;
    __syncthreads();
    perm[cloff[c] + gbase[c] + lrank] = r;
}

// ---------------------------------------------------------------------------
// fp32 -> (hi,lo) bf16 split, elementwise (coalesced)
__global__ void split_mat(const float* __restrict__ A, unsigned short* __restrict__ hi,
                          unsigned short* __restrict__ lo, int total) {
    int i = blockIdx.x * blockDim.x + threadIdx.x;
    if (i >= total) return;
    unsigned short h, l;
    split2(A[i], h, l);
    hi[i] = h; lo[i] = l;
}

// LDS-tiled transpose+split: W [m][K][N] fp32 -> [m][N][K] split bf16, coalesced
__global__ __launch_bounds__(256) void transpose_split64(const float* __restrict__ W,
                                                         unsigned short* __restrict__ hi,
                                                         unsigned short* __restrict__ lo,
                                                         int K, int N) {
    __shared__ float ld[64 * 65];
    int m = blockIdx.z;
    int k0 = blockIdx.x * 64, n0 = blockIdx.y * 64;
    const float* Wm = W + (size_t)m * K * N;
    int tx = threadIdx.x & 63, ty = threadIdx.x >> 6;
#pragma unroll
    for (int rr = 0; rr < 16; rr++) {
        int kl = rr * 4 + ty;
        ld[tx * 65 + kl] = Wm[(size_t)(k0 + kl) * N + n0 + tx];
    }
    __syncthreads();
    size_t obase = (size_t)m * N * K;
#pragma unroll
    for (int rr = 0; rr < 16; rr++) {
        int nl = rr * 4 + ty;
        float v = ld[nl * 65 + tx];
        unsigned short h, l;
        split2(v, h, l);
        size_t o = obase + (size_t)(n0 + nl) * K + k0 + tx;
        hi[o] = h;
        lo[o] = l;
    }
}

// ---------------------------------------------------------------------------
// split-bf16 MFMA GEMM: C[M,N] = A[M,K] @ B[K,N], B passed as B^T ([N][K]).
// Staging: row-major LDS (4 lanes x 16B contiguous per row = coalesced), with
// XOR swizzle: chunk ch of row r stored at pos ch^((r>>1)&3). Fragment reads
// then cover all 8 LDS bank-groups with 2 lanes each -> conflict-free (2-way).
__global__ __launch_bounds__(256) void gemm_mfma(
        const unsigned short* __restrict__ Ahi, const unsigned short* __restrict__ Alo,
        const unsigned short* __restrict__ BThi, const unsigned short* __restrict__ BTlo,
        float* __restrict__ C, int M, int K, int N) {
    __shared__ unsigned short sAh[4096], sAl[4096], sBh[4096], sBl[4096];
    int t = threadIdx.x;
    int wv = t >> 6, lane = t & 63, quad = lane >> 4, l15 = lane & 15;
    int m0 = blockIdx.x * 128, n0 = blockIdx.y * 128;
    int m0w = (wv >> 1) * 64, n0w = (wv & 1) * 64;
    floatx4 zero = {0.f, 0.f, 0.f, 0.f};
    floatx4 acc[4][4];
#pragma unroll
    for (int i = 0; i < 4; i++)
#pragma unroll
        for (int j = 0; j < 4; j++) acc[i][j] = zero;

    for (int kk = 0; kk < K; kk += 32) {
#pragma unroll
        for (int c = 0; c < 2; c++) {
            int s = t + c * 256;                 // slot in [0,512)
            int row = s >> 2, pos = s & 3;
            int ch = pos ^ ((row >> 1) & 3);     // XOR-swizzled chunk
            int arow = m0 + row; if (arow > M - 1) arow = M - 1;
            int brow = n0 + row; if (brow > N - 1) brow = N - 1;
            size_t aoff = (size_t)arow * K + kk + ch * 8;
            size_t boff = (size_t)brow * K + kk + ch * 8;
            gload16(Ahi + aoff, &sAh[s * 8]);
            gload16(Alo + aoff, &sAl[s * 8]);
            gload16(BThi + boff, &sBh[s * 8]);
            gload16(BTlo + boff, &sBl[s * 8]);
        }
        __syncthreads();
        short8 ah[4], al[4], bh[4], bl[4];
        int qsw = quad;  // chunk needed = quad; slot pos = quad ^ ((l15>>1)&3)
        int posq = qsw ^ ((l15 >> 1) & 3);
#pragma unroll
        for (int i = 0; i < 4; i++) {
            int sl = (m0w + i * 16 + l15) * 4 + posq;
            ah[i] = *(const short8*)&sAh[sl * 8];
            al[i] = *(const short8*)&sAl[sl * 8];
        }
#pragma unroll
        for (int j = 0; j < 4; j++) {
            int sl = (n0w + j * 16 + l15) * 4 + posq;
            bh[j] = *(const short8*)&sBh[sl * 8];
            bl[j] = *(const short8*)&sBl[sl * 8];
        }
#pragma unroll
        for (int i = 0; i < 4; i++)
#pragma unroll
            for (int j = 0; j < 4; j++) {
                acc[i][j] = __builtin_amdgcn_mfma_f32_16x16x32_bf16(ah[i], bh[j], acc[i][j], 0, 0, 0);
                acc[i][j] = __builtin_amdgcn_mfma_f32_16x16x32_bf16(ah[i], bl[j], acc[i][j], 0, 0, 0);
                acc[i][j] = __builtin_amdgcn_mfma_f32_16x16x32_bf16(al[i], bh[j], acc[i][j], 0, 0, 0);
            }
        __syncthreads();
    }
#pragma unroll
    for (int i = 0; i < 4; i++) {
        int gr = m0 + m0w + i * 16 + quad * 4;
#pragma unroll
        for (int r = 0; r < 4; r++) {
            if (gr + r < M) {
#pragma unroll
                for (int j = 0; j < 4; j++)
                    C[(size_t)(gr + r) * N + n0 + n0w + j * 16 + l15] = acc[i][j][r];
            }
        }
    }
}

// ---------------------------------------------------------------------------
// GCN aggregate; 4-way unrolled neighbor loop for memory-level parallelism
__global__ __launch_bounds__(256) void aggregate_k(const float* __restrict__ tmp,
                                                   const int* __restrict__ drug_ptr,
                                                   const int* __restrict__ adj_drug,
                                                   const int* __restrict__ prot_ptr,
                                                   const int* __restrict__ adj_prot,
                                                   const float* __restrict__ dinv,
                                                   const float* __restrict__ bias,
                                                   float* __restrict__ outf,
                                                   unsigned short* __restrict__ outhi,
                                                   unsigned short* __restrict__ outlo) {
    int wave = (blockIdx.x * blockDim.x + threadIdx.x) >> 6;
    int lane = threadIdx.x & 63;
    if (wave >= N_NODES) return;
    int i = wave;
    const int* adj;
    int s, e;
    if (i < NUM_DRUGS) { s = drug_ptr[i]; e = drug_ptr[i + 1]; adj = adj_drug; }
    else               { s = prot_ptr[i]; e = prot_ptr[i + 1]; adj = adj_prot; }
    float di = dinv[i];
    float4 a0 = make_float4(0.f, 0.f, 0.f, 0.f);
    float4 a1 = a0, a2 = a0, a3 = a0;
    int idx = s;
    for (; idx + 4 <= e; idx += 4) {
        int j0 = adj[idx + 0], j1 = adj[idx + 1], j2 = adj[idx + 2], j3 = adj[idx + 3];
        float d0 = dinv[j0], d1 = dinv[j1], d2 = dinv[j2], d3 = dinv[j3];
        float4 v0 = ((const float4*)(tmp + (size_t)j0 * CDIM))[lane];
        float4 v1 = ((const float4*)(tmp + (size_t)j1 * CDIM))[lane];
        float4 v2 = ((const float4*)(tmp + (size_t)j2 * CDIM))[lane];
        float4 v3 = ((const float4*)(tmp + (size_t)j3 * CDIM))[lane];
        a0 = f4fma(v0, d0, a0);
        a1 = f4fma(v1, d1, a1);
        a2 = f4fma(v2, d2, a2);
        a3 = f4fma(v3, d3, a3);
    }
    for (; idx < e; idx++) {
        int j = adj[idx];
        float dj = dinv[j];
        float4 v = ((const float4*)(tmp + (size_t)j * CDIM))[lane];
        a0 = f4fma(v, dj, a0);
    }
    float4 self = ((const float4*)(tmp + (size_t)i * CDIM))[lane];
    float4 acc;
    acc.x = (a0.x + a1.x) + (a2.x + a3.x) + self.x * di;
    acc.y = (a0.y + a1.y) + (a2.y + a3.y) + self.y * di;
    acc.z = (a0.z + a1.z) + (a2.z + a3.z) + self.z * di;
    acc.w = (a0.w + a1.w) + (a2.w + a3.w) + self.w * di;
    float4 bv = ((const float4*)bias)[lane];
    float4 r;
    r.x = fmaxf(fmaf(acc.x, di, bv.x), 0.f);
    r.y = fmaxf(fmaf(acc.y, di, bv.y), 0.f);
    r.z = fmaxf(fmaf(acc.z, di, bv.z), 0.f);
    r.w = fmaxf(fmaf(acc.w, di, bv.w), 0.f);
    if (outhi) {
        ushort4 h, l;
        split2(r.x, h.x, l.x); split2(r.y, h.y, l.y);
        split2(r.z, h.z, l.z); split2(r.w, h.w, l.w);
        *(ushort4*)&outhi[(size_t)i * CDIM + lane * 4] = h;
        *(ushort4*)&outlo[(size_t)i * CDIM + lane * 4] = l;
    } else {
        ((float4*)(outf + (size_t)i * CDIM))[lane] = r;
    }
}

// scatter-mean pool -> split-bf16 graph embeddings; 4-way unrolled
__global__ __launch_bounds__(256) void pool_drugs(const float* __restrict__ h2,
                                                  unsigned short* __restrict__ Ghi,
                                                  unsigned short* __restrict__ Glo,
                                                  const int* __restrict__ drug_ptr,
                                                  const int* __restrict__ adj_drug) {
    int wave = (blockIdx.x * blockDim.x + threadIdx.x) >> 6;
    int lane = threadIdx.x & 63;
    if (wave >= NUM_DRUGS) return;
    int d = wave;
    int s = drug_ptr[d], e = drug_ptr[d + 1];
    float4 a0 = make_float4(0.f, 0.f, 0.f, 0.f);
    float4 a1 = a0, a2 = a0, a3 = a0;
    int idx = s;
    for (; idx + 4 <= e; idx += 4) {
        int j0 = adj_drug[idx + 0], j1 = adj_drug[idx + 1];
        int j2 = adj_drug[idx + 2], j3 = adj_drug[idx + 3];
        float4 v0 = ((const float4*)(h2 + (size_t)j0 * CDIM))[lane];
        float4 v1 = ((const float4*)(h2 + (size_t)j1 * CDIM))[lane];
        float4 v2 = ((const float4*)(h2 + (size_t)j2 * CDIM))[lane];
        float4 v3 = ((const float4*)(h2 + (size_t)j3 * CDIM))[lane];
        a0.x += v0.x; a0.y += v0.y; a0.z += v0.z; a0.w += v0.w;
        a1.x += v1.x; a1.y += v1.y; a1.z += v1.z; a1.w += v1.w;
        a2.x += v2.x; a2.y += v2.y; a2.z += v2.z; a2.w += v2.w;
        a3.x += v3.x; a3.y += v3.y; a3.z += v3.z; a3.w += v3.w;
    }
    for (; idx < e; idx++) {
        int j = adj_drug[idx];
        float4 v = ((const float4*)(h2 + (size_t)j * CDIM))[lane];
        a0.x += v.x; a0.y += v.y; a0.z += v.z; a0.w += v.w;
    }
    float4 acc;
    acc.x = (a0.x + a1.x) + (a2.x + a3.x);
    acc.y = (a0.y + a1.y) + (a2.y + a3.y);
    acc.z = (a0.z + a1.z) + (a2.z + a3.z);
    acc.w = (a0.w + a1.w) + (a2.w + a3.w);
    int cnt = e - s;
    float sc = 1.f / (float)(cnt > 1 ? cnt : 1);
    acc.x *= sc; acc.y *= sc; acc.z *= sc; acc.w *= sc;
    ushort4 h, l;
    split2(acc.x, h.x, l.x); split2(acc.y, h.y, l.y);
    split2(acc.z, h.z, l.z); split2(acc.w, h.w, l.w);
    *(ushort4*)&Ghi[(size_t)d * CDIM + lane * 4] = h;
    *(ushort4*)&Glo[(size_t)d * CDIM + lane * 4] = l;
}

__global__ void out_init(float* __restrict__ outp, const int* __restrict__ ecl,
                         const float* __restrict__ b2) {
    int i = blockIdx.x * blockDim.x + threadIdx.x;
    if (i < BATCH) outp[i] = b2[ecl[i]];
}

// ---------------------------------------------------------------------------
// grouped MoE MLP via split-bf16 MFMA; 128x128 tile (R4 config), row-major
// XOR-swizzled LDS (coalesced staging AND conflict-free frag reads);
// fused relu+b1 and [512,1] layer-2 epilogue.
__global__ __launch_bounds__(256) void mlp_mfma(
        const unsigned short* __restrict__ Ghi, const unsigned short* __restrict__ Glo,
        const unsigned short* __restrict__ W1Thi, const unsigned short* __restrict__ W1Tlo,
        const float* __restrict__ b1, const float* __restrict__ W2,
        const int* __restrict__ ddb, const int* __restrict__ perm,
        const int* __restrict__ cloff, float* __restrict__ outp) {
    int e = blockIdx.z;
    int lo_ = cloff[e], hi_ = cloff[e + 1];
    int base = lo_ + blockIdx.y * 128;
    if (base >= hi_) return;
    __shared__ unsigned short sAh[4096], sAl[4096], sBh[4096], sBl[4096];
    __shared__ int rid[128], g0s[128], g1s[128];
    int t = threadIdx.x;
    if (t < 128) {
        int idx = base + t;
        if (idx < hi_) {
            int r = perm[idx];
            rid[t] = r;
            g0s[t] = ddb[r] * CDIM;
            g1s[t] = ddb[BATCH + r] * CDIM;
        } else { rid[t] = -1; g0s[t] = 0; g1s[t] = 0; }
    }
    __syncthreads();
    int wv = t >> 6, lane = t & 63, quad = lane >> 4, l15 = lane & 15;
    int n0 = blockIdx.x * 128;
    int m0w = (wv >> 1) * 64, n0w = (wv & 1) * 64;
    const unsigned short* W1eh = W1Thi + (size_t)e * HID * HID;
    const unsigned short* W1el = W1Tlo + (size_t)e * HID * HID;
    floatx4 zero = {0.f, 0.f, 0.f, 0.f};
    floatx4 acc[4][4];
#pragma unroll
    for (int i = 0; i < 4; i++)
#pragma unroll
        for (int j = 0; j < 4; j++) acc[i][j] = zero;

    for (int kk = 0; kk < 2 * CDIM; kk += 32) {
        const int* gsel = (kk < CDIM) ? g0s : g1s;
        int kbase = kk & (CDIM - 1);
#pragma unroll
        for (int c = 0; c < 2; c++) {
            int s = t + c * 256;                 // slot in [0,512)
            int row = s >> 2, pos = s & 3;
            int ch = pos ^ ((row >> 1) & 3);     // XOR-swizzled chunk
            size_t aoff = (size_t)gsel[row] + kbase + ch * 8;
            size_t boff = (size_t)(n0 + row) * HID + kk + ch * 8;
            gload16(Ghi + aoff, &sAh[s * 8]);
            gload16(Glo + aoff, &sAl[s * 8]);
            gload16(W1eh + boff, &sBh[s * 8]);
            gload16(W1el + boff, &sBl[s * 8]);
        }
        __syncthreads();
        short8 ah[4], al[4], bh[4], bl[4];
        int posq = quad ^ ((l15 >> 1) & 3);
#pragma unroll
        for (int i = 0; i < 4; i++) {
            int sl = (m0w + i * 16 + l15) * 4 + posq;
            ah[i] = *(const short8*)&sAh[sl * 8];
            al[i] = *(const short8*)&sAl[sl * 8];
        }
#pragma unroll
        for (int j = 0; j < 4; j++) {
            int sl = (n0w + j * 16 + l15) * 4 + posq;
            bh[j] = *(const short8*)&sBh[sl * 8];
            bl[j] = *(const short8*)&sBl[sl * 8];
        }
#pragma unroll
        for (int i = 0; i < 4; i++)
#pragma unroll
            for (int j = 0; j < 4; j++) {
                acc[i][j] = __builtin_amdgcn_mfma_f32_16x16x32_bf16(ah[i], bh[j], acc[i][j], 0, 0, 0);
                acc[i][j] = __builtin_amdgcn_mfma_f32_16x16x32_bf16(ah[i], bl[j], acc[i][j], 0, 0, 0);
                acc[i][j] = __builtin_amdgcn_mfma_f32_16x16x32_bf16(al[i], bh[j], acc[i][j], 0, 0, 0);
            }
        __syncthreads();
    }
    const float* b1e = b1 + (size_t)e * HID;
    const float* W2e = W2 + (size_t)e * HID;
#pragma unroll
    for (int i = 0; i < 4; i++) {
#pragma unroll
        for (int r = 0; r < 4; r++) {
            float s = 0.f;
#pragma unroll
            for (int j = 0; j < 4; j++) {
                int col = n0 + n0w + j * 16 + l15;
                float h = fmaxf(acc[i][j][r] + b1e[col], 0.f);
                s = fmaf(h, W2e[col], s);
            }
            s += __shfl_xor(s, 1, 16);
            s += __shfl_xor(s, 2, 16);
            s += __shfl_xor(s, 4, 16);
            s += __shfl_xor(s, 8, 16);
            if (l15 == 0) {
                int rowl = m0w + i * 16 + quad * 4 + r;
                int rr2 = rid[rowl];
                if (rr2 >= 0) atomicAdd(&outp[rr2], s);
            }
        }
    }
}

// ---------------------------------------------------------------------------
extern "C" void kernel_launch(void* const* d_in, const int* in_sizes, int n_in,
                              void* d_out, int out_size, void* d_ws, size_t ws_size,
                              hipStream_t stream) {
    const float* x   = (const float*)d_in[0];
    const int* ei    = (const int*)d_in[1];
    const int* ddb   = (const int*)d_in[2];
    const int* ecl   = (const int*)d_in[3];
    const float* Wg1 = (const float*)d_in[5];
    const float* bg1 = (const float*)d_in[6];
    const float* Wg2 = (const float*)d_in[7];
    const float* bg2 = (const float*)d_in[8];
    const float* W1  = (const float*)d_in[9];
    const float* b1  = (const float*)d_in[10];
    const float* W2  = (const float*)d_in[11];
    const float* b2  = (const float*)d_in[12];
    float* outp = (float*)d_out;

    char* p = (char*)d_ws;
    auto alloc = [&](size_t bytes) {
        char* r = p;
        p += (bytes + 255) & ~size_t(255);
        return (void*)r;
    };
    const size_t NC = (size_t)N_NODES * CDIM;
    float* tmp            = (float*)alloc(sizeof(float) * NC);
    unsigned short* h1hi  = (unsigned short*)alloc(2 * NC);
    unsigned short* h1lo  = (unsigned short*)alloc(2 * NC);
    char* xh2_blk         = (char*)alloc(4 * NC);                 // xhi+xlo, later h2
    unsigned short* xhi   = (unsigned short*)xh2_blk;
    unsigned short* xlo   = (unsigned short*)(xh2_blk + 2 * NC);
    float* h2             = (float*)xh2_blk;
    unsigned short* Ghi   = (unsigned short*)alloc(2 * NUM_DRUGS * CDIM);
    unsigned short* Glo   = (unsigned short*)alloc(2 * NUM_DRUGS * CDIM);
    unsigned short* wg1Th = (unsigned short*)alloc(2 * CDIM * CDIM);
    unsigned short* wg1Tl = (unsigned short*)alloc(2 * CDIM * CDIM);
    unsigned short* wg2Th = (unsigned short*)alloc(2 * CDIM * CDIM);
    unsigned short* wg2Tl = (unsigned short*)alloc(2 * CDIM * CDIM);
    unsigned short* W1Th  = (unsigned short*)alloc(2 * (size_t)N_CL * HID * HID);
    unsigned short* W1Tl  = (unsigned short*)alloc(2 * (size_t)N_CL * HID * HID);
    float* dinv    = (float*)alloc(sizeof(float) * N_NODES);
    int* cnt_d     = (int*)alloc(sizeof(int) * NUM_DRUGS * STRD);
    int* cur_d     = (int*)alloc(sizeof(int) * NUM_DRUGS * STRD);
    int* cnt_p     = (int*)alloc(sizeof(int) * N_NODES * STRP);
    int* cur_p     = (int*)alloc(sizeof(int) * N_NODES * STRP);
    int* drug_ptr  = (int*)alloc(sizeof(int) * (NUM_DRUGS + 1));
    int* prot_ptr  = (int*)alloc(sizeof(int) * (N_NODES + 1));
    int* adj_drug  = (int*)alloc(sizeof(int) * NUM_DPI);
    int* adj_prot  = (int*)alloc(sizeof(int) * NUM_DPI);
    int* clcnt     = (int*)alloc(sizeof(int) * N_CL * STRD);
    int* curcl     = (int*)alloc(sizeof(int) * N_CL * STRD);
    int* cloff     = (int*)alloc(sizeof(int) * (N_CL + 1));
    int* perm      = (int*)alloc(sizeof(int) * BATCH);

    // graph prep
    zero_counts<<<(N_NODES + 255) / 256, 256, 0, stream>>>(cnt_d, cur_d, cnt_p, cur_p,
                                                           clcnt, curcl);
    count_dpi<<<(NUM_DPI + 255) / 256, 256, 0, stream>>>(ei, cnt_d, cnt_p);
    count_cl<<<BATCH / 256, 256, 0, stream>>>(ecl, clcnt);
    scan3<<<3, 1024, 0, stream>>>(cnt_d, cnt_p, clcnt, drug_ptr, prot_ptr, cloff);
    fill_dpi<<<(NUM_DPI + 255) / 256, 256, 0, stream>>>(ei, drug_ptr, cur_d, adj_drug,
                                                        prot_ptr, cur_p, adj_prot, dinv);
    fill_perm<<<BATCH / 256, 256, 0, stream>>>(ecl, curcl, cloff, perm);
    // weight/activation splits (coalesced)
    split_mat<<<((int)NC + 255) / 256, 256, 0, stream>>>(x, xhi, xlo, (int)NC);
    transpose_split64<<<dim3(CDIM / 64, CDIM / 64, 1), 256, 0, stream>>>(
        Wg1, wg1Th, wg1Tl, CDIM, CDIM);
    transpose_split64<<<dim3(CDIM / 64, CDIM / 64, 1), 256, 0, stream>>>(
        Wg2, wg2Th, wg2Tl, CDIM, CDIM);
    transpose_split64<<<dim3(HID / 64, HID / 64, N_CL), 256, 0, stream>>>(
        W1, W1Th, W1Tl, HID, HID);
    // GCN layer 1
    gemm_mfma<<<dim3((N_NODES + 127) / 128, CDIM / 128), 256, 0, stream>>>(
        xhi, xlo, wg1Th, wg1Tl, tmp, N_NODES, CDIM, CDIM);
    aggregate_k<<<(N_NODES * 64 + 255) / 256, 256, 0, stream>>>(
        tmp, drug_ptr, adj_drug, prot_ptr, adj_prot, dinv, bg1, nullptr, h1hi, h1lo);
    // GCN layer 2
    gemm_mfma<<<dim3((N_NODES + 127) / 128, CDIM / 128), 256, 0, stream>>>(
        h1hi, h1lo, wg2Th, wg2Tl, tmp, N_NODES, CDIM, CDIM);
    aggregate_k<<<(N_NODES * 64 + 255) / 256, 256, 0, stream>>>(
        tmp, drug_ptr, adj_drug, prot_ptr, adj_prot, dinv, bg2, h2, nullptr, nullptr);
    // pool -> split graph embeddings
    pool_drugs<<<(NUM_DRUGS * 64 + 255) / 256, 256, 0, stream>>>(h2, Ghi, Glo,
                                                                 drug_ptr, adj_drug);
    // MoE MLP (R4 grid: 4 col-tiles x 24 row-tiles x 8 experts)
    out_init<<<(BATCH + 255) / 256, 256, 0, stream>>>(outp, ecl, b2);
    mlp_mfma<<<dim3(HID / 128, 24, N_CL), 256, 0, stream>>>(
        Ghi, Glo, W1Th, W1Tl, b1, W2, ddb, perm, cloff, outp);
}

// Round 9
// 387.717 us; speedup vs baseline: 1.1496x; 1.0437x over previous
//
#include <hip/hip_runtime.h>
#include <hip/hip_bf16.h>

// Problem constants (fixed by reference)
#define N_NODES 20000
#define NUM_DRUGS 2048
#define NUM_DPI 200000
#define E2 400000          // 2*NUM_DPI directed edges
#define CDIM 256           // IN_C == EMB == 256
#define HID 512
#define N_CL 8
#define BATCH 16384
#define HN 8192            // H cols = 8 experts x 2 halves x 512

#define STRD 32            // drug counter padding (ints) = 1 line per counter
#define STRP 16            // protein counter padding

typedef __attribute__((ext_vector_type(8))) short short8;   // 8 bf16 (MFMA A/B frag)
typedef __attribute__((ext_vector_type(4))) float floatx4;  // MFMA C/D frag

__device__ inline unsigned short f2bf(float f) {
    unsigned u = __float_as_uint(f);
    u += 0x7fff + ((u >> 16) & 1);   // RNE
    return (unsigned short)(u >> 16);
}
__device__ inline float bf2f(unsigned short h) {
    return __uint_as_float((unsigned)h << 16);
}
__device__ inline void split2(float v, unsigned short& h, unsigned short& l) {
    h = f2bf(v);
    l = f2bf(v - bf2f(h));
}
__device__ inline void gload16(const void* g, void* l) {
    __builtin_amdgcn_global_load_lds(
        (const __attribute__((address_space(1))) void*)g,
        (__attribute__((address_space(3))) void*)l, 16, 0, 0);
}
__device__ inline float4 f4fma(float4 v, float s, float4 a) {
    a.x = fmaf(v.x, s, a.x); a.y = fmaf(v.y, s, a.y);
    a.z = fmaf(v.z, s, a.z); a.w = fmaf(v.w, s, a.w);
    return a;
}

// ---------------------------------------------------------------------------
__global__ void zero_counts(int* cnt_d, int* cur_d, int* cnt_p, int* cur_p) {
    int i = blockIdx.x * blockDim.x + threadIdx.x;
    if (i < N_NODES) { cnt_p[i * STRP] = 0; cur_p[i * STRP] = 0; }
    if (i < NUM_DRUGS) { cnt_d[i * STRD] = 0; cur_d[i * STRD] = 0; }
}

// count DPI pairs into padded per-drug / per-protein histograms
__global__ void count_dpi(const int* __restrict__ ei, int* cnt_d, int* cnt_p) {
    int e = blockIdx.x * blockDim.x + threadIdx.x;
    if (e >= NUM_DPI) return;
    atomicAdd(&cnt_d[ei[e] * STRD], 1);          // drug id of pair e
    atomicAdd(&cnt_p[ei[E2 + e] * STRP], 1);     // protein id of pair e
}

// generic strided single-block exclusive scan
__device__ void scan_dev(const int* counts, int stride, int* ptr, int n) {
    __shared__ int sums[1024];
    int t = threadIdx.x;
    int per = (n + 1023) / 1024;
    int start = t * per;
    int end = start + per; if (end > n) end = n;
    int s = 0;
    for (int i = start; i < end; i++) s += counts[i * stride];
    sums[t] = s;
    __syncthreads();
    for (int off = 1; off < 1024; off <<= 1) {
        int v = (t >= off) ? sums[t - off] : 0;
        __syncthreads();
        sums[t] += v;
        __syncthreads();
    }
    int base = (t == 0) ? 0 : sums[t - 1];
    for (int i = start; i < end; i++) {
        ptr[i] = base;
        base += counts[i * stride];
    }
    if (t == 1023) ptr[n] = sums[1023];
}

__global__ void scan2(const int* cnt_d, const int* cnt_p,
                      int* drug_ptr, int* prot_ptr) {
    if (blockIdx.x == 0) scan_dev(cnt_d, STRD, drug_ptr, NUM_DRUGS);
    else scan_dev(cnt_p, STRP, prot_ptr, N_NODES);
}

// fill both adjacency lists from DPI pairs; padded counters kill line ping-pong
__global__ void fill_dpi(const int* __restrict__ ei,
                         const int* __restrict__ drug_ptr, int* cur_d, int* adj_drug,
                         const int* __restrict__ prot_ptr, int* cur_p, int* adj_prot,
                         float* __restrict__ dinv) {
    int e = blockIdx.x * blockDim.x + threadIdx.x;
    if (e < NUM_DPI) {
        int d = ei[e];
        int p = ei[E2 + e];
        int posd = drug_ptr[d] + atomicAdd(&cur_d[d * STRD], 1);
        int posp = prot_ptr[p] + atomicAdd(&cur_p[p * STRP], 1);
        adj_drug[posd] = p;
        adj_prot[posp] = d;
    }
    if (e < N_NODES) {
        int deg = (e < NUM_DRUGS) ? (drug_ptr[e + 1] - drug_ptr[e])
                                  : (prot_ptr[e + 1] - prot_ptr[e]);
        dinv[e] = rsqrtf((float)(deg + 1));
    }
}

// ---------------------------------------------------------------------------
// fp32 -> (hi,lo) bf16 split, elementwise (coalesced)
__global__ void split_mat(const float* __restrict__ A, unsigned short* __restrict__ hi,
                          unsigned short* __restrict__ lo, int total) {
    int i = blockIdx.x * blockDim.x + threadIdx.x;
    if (i >= total) return;
    unsigned short h, l;
    split2(A[i], h, l);
    hi[i] = h; lo[i] = l;
}

// LDS-tiled transpose+split: W [m][K][N] fp32 -> [m][N][K] split bf16, coalesced
__global__ __launch_bounds__(256) void transpose_split64(const float* __restrict__ W,
                                                         unsigned short* __restrict__ hi,
                                                         unsigned short* __restrict__ lo,
                                                         int K, int N) {
    __shared__ float ld[64 * 65];
    int m = blockIdx.z;
    int k0 = blockIdx.x * 64, n0 = blockIdx.y * 64;
    const float* Wm = W + (size_t)m * K * N;
    int tx = threadIdx.x & 63, ty = threadIdx.x >> 6;
#pragma unroll
    for (int rr = 0; rr < 16; rr++) {
        int kl = rr * 4 + ty;
        ld[tx * 65 + kl] = Wm[(size_t)(k0 + kl) * N + n0 + tx];
    }
    __syncthreads();
    size_t obase = (size_t)m * N * K;
#pragma unroll
    for (int rr = 0; rr < 16; rr++) {
        int nl = rr * 4 + ty;
        float v = ld[nl * 65 + tx];
        unsigned short h, l;
        split2(v, h, l);
        size_t o = obase + (size_t)(n0 + nl) * K + k0 + tx;
        hi[o] = h;
        lo[o] = l;
    }
}

// ---------------------------------------------------------------------------
// split-bf16 MFMA GEMM: C[M,N] = A[M,K] @ B[K,N], B passed as B^T ([N][K]).
// Row-major XOR-swizzled LDS: coalesced staging AND conflict-free frag reads.
__global__ __launch_bounds__(256) void gemm_mfma(
        const unsigned short* __restrict__ Ahi, const unsigned short* __restrict__ Alo,
        const unsigned short* __restrict__ BThi, const unsigned short* __restrict__ BTlo,
        float* __restrict__ C, int M, int K, int N) {
    __shared__ unsigned short sAh[4096], sAl[4096], sBh[4096], sBl[4096];
    int t = threadIdx.x;
    int wv = t >> 6, lane = t & 63, quad = lane >> 4, l15 = lane & 15;
    int m0 = blockIdx.x * 128, n0 = blockIdx.y * 128;
    int m0w = (wv >> 1) * 64, n0w = (wv & 1) * 64;
    floatx4 zero = {0.f, 0.f, 0.f, 0.f};
    floatx4 acc[4][4];
#pragma unroll
    for (int i = 0; i < 4; i++)
#pragma unroll
        for (int j = 0; j < 4; j++) acc[i][j] = zero;

    for (int kk = 0; kk < K; kk += 32) {
#pragma unroll
        for (int c = 0; c < 2; c++) {
            int s = t + c * 256;                 // slot in [0,512)
            int row = s >> 2, pos = s & 3;
            int ch = pos ^ ((row >> 1) & 3);     // XOR-swizzled chunk
            int arow = m0 + row; if (arow > M - 1) arow = M - 1;
            int brow = n0 + row; if (brow > N - 1) brow = N - 1;
            size_t aoff = (size_t)arow * K + kk + ch * 8;
            size_t boff = (size_t)brow * K + kk + ch * 8;
            gload16(Ahi + aoff, &sAh[s * 8]);
            gload16(Alo + aoff, &sAl[s * 8]);
            gload16(BThi + boff, &sBh[s * 8]);
            gload16(BTlo + boff, &sBl[s * 8]);
        }
        __syncthreads();
        short8 ah[4], al[4], bh[4], bl[4];
        int posq = quad ^ ((l15 >> 1) & 3);
#pragma unroll
        for (int i = 0; i < 4; i++) {
            int sl = (m0w + i * 16 + l15) * 4 + posq;
            ah[i] = *(const short8*)&sAh[sl * 8];
            al[i] = *(const short8*)&sAl[sl * 8];
        }
#pragma unroll
        for (int j = 0; j < 4; j++) {
            int sl = (n0w + j * 16 + l15) * 4 + posq;
            bh[j] = *(const short8*)&sBh[sl * 8];
            bl[j] = *(const short8*)&sBl[sl * 8];
        }
#pragma unroll
        for (int i = 0; i < 4; i++)
#pragma unroll
            for (int j = 0; j < 4; j++) {
                acc[i][j] = __builtin_amdgcn_mfma_f32_16x16x32_bf16(ah[i], bh[j], acc[i][j], 0, 0, 0);
                acc[i][j] = __builtin_amdgcn_mfma_f32_16x16x32_bf16(ah[i], bl[j], acc[i][j], 0, 0, 0);
                acc[i][j] = __builtin_amdgcn_mfma_f32_16x16x32_bf16(al[i], bh[j], acc[i][j], 0, 0, 0);
            }
        __syncthreads();
    }
#pragma unroll
    for (int i = 0; i < 4; i++) {
        int gr = m0 + m0w + i * 16 + quad * 4;
#pragma unroll
        for (int r = 0; r < 4; r++) {
            if (gr + r < M) {
#pragma unroll
                for (int j = 0; j < 4; j++)
                    C[(size_t)(gr + r) * N + n0 + n0w + j * 16 + l15] = acc[i][j][r];
            }
        }
    }
}

// ---------------------------------------------------------------------------
// GCN aggregate; 4-way unrolled neighbor loop for memory-level parallelism
__global__ __launch_bounds__(256) void aggregate_k(const float* __restrict__ tmp,
                                                   const int* __restrict__ drug_ptr,
                                                   const int* __restrict__ adj_drug,
                                                   const int* __restrict__ prot_ptr,
                                                   const int* __restrict__ adj_prot,
                                                   const float* __restrict__ dinv,
                                                   const float* __restrict__ bias,
                                                   float* __restrict__ outf,
                                                   unsigned short* __restrict__ outhi,
                                                   unsigned short* __restrict__ outlo) {
    int wave = (blockIdx.x * blockDim.x + threadIdx.x) >> 6;
    int lane = threadIdx.x & 63;
    if (wave >= N_NODES) return;
    int i = wave;
    const int* adj;
    int s, e;
    if (i < NUM_DRUGS) { s = drug_ptr[i]; e = drug_ptr[i + 1]; adj = adj_drug; }
    else               { s = prot_ptr[i]; e = prot_ptr[i + 1]; adj = adj_prot; }
    float di = dinv[i];
    float4 a0 = make_float4(0.f, 0.f, 0.f, 0.f);
    float4 a1 = a0, a2 = a0, a3 = a0;
    int idx = s;
    for (; idx + 4 <= e; idx += 4) {
        int j0 = adj[idx + 0], j1 = adj[idx + 1], j2 = adj[idx + 2], j3 = adj[idx + 3];
        float d0 = dinv[j0], d1 = dinv[j1], d2 = dinv[j2], d3 = dinv[j3];
        float4 v0 = ((const float4*)(tmp + (size_t)j0 * CDIM))[lane];
        float4 v1 = ((const float4*)(tmp + (size_t)j1 * CDIM))[lane];
        float4 v2 = ((const float4*)(tmp + (size_t)j2 * CDIM))[lane];
        float4 v3 = ((const float4*)(tmp + (size_t)j3 * CDIM))[lane];
        a0 = f4fma(v0, d0, a0);
        a1 = f4fma(v1, d1, a1);
        a2 = f4fma(v2, d2, a2);
        a3 = f4fma(v3, d3, a3);
    }
    for (; idx < e; idx++) {
        int j = adj[idx];
        float dj = dinv[j];
        float4 v = ((const float4*)(tmp + (size_t)j * CDIM))[lane];
        a0 = f4fma(v, dj, a0);
    }
    float4 self = ((const float4*)(tmp + (size_t)i * CDIM))[lane];
    float4 acc;
    acc.x = (a0.x + a1.x) + (a2.x + a3.x) + self.x * di;
    acc.y = (a0.y + a1.y) + (a2.y + a3.y) + self.y * di;
    acc.z = (a0.z + a1.z) + (a2.z + a3.z) + self.z * di;
    acc.w = (a0.w + a1.w) + (a2.w + a3.w) + self.w * di;
    float4 bv = ((const float4*)bias)[lane];
    float4 r;
    r.x = fmaxf(fmaf(acc.x, di, bv.x), 0.f);
    r.y = fmaxf(fmaf(acc.y, di, bv.y), 0.f);
    r.z = fmaxf(fmaf(acc.z, di, bv.z), 0.f);
    r.w = fmaxf(fmaf(acc.w, di, bv.w), 0.f);
    if (outhi) {
        ushort4 h, l;
        split2(r.x, h.x, l.x); split2(r.y, h.y, l.y);
        split2(r.z, h.z, l.z); split2(r.w, h.w, l.w);
        *(ushort4*)&outhi[(size_t)i * CDIM + lane * 4] = h;
        *(ushort4*)&outlo[(size_t)i * CDIM + lane * 4] = l;
    } else {
        ((float4*)(outf + (size_t)i * CDIM))[lane] = r;
    }
}

// scatter-mean pool -> split-bf16 graph embeddings; 4-way unrolled
__global__ __launch_bounds__(256) void pool_drugs(const float* __restrict__ h2,
                                                  unsigned short* __restrict__ Ghi,
                                                  unsigned short* __restrict__ Glo,
                                                  const int* __restrict__ drug_ptr,
                                                  const int* __restrict__ adj_drug) {
    int wave = (blockIdx.x * blockDim.x + threadIdx.x) >> 6;
    int lane = threadIdx.x & 63;
    if (wave >= NUM_DRUGS) return;
    int d = wave;
    int s = drug_ptr[d], e = drug_ptr[d + 1];
    float4 a0 = make_float4(0.f, 0.f, 0.f, 0.f);
    float4 a1 = a0, a2 = a0, a3 = a0;
    int idx = s;
    for (; idx + 4 <= e; idx += 4) {
        int j0 = adj_drug[idx + 0], j1 = adj_drug[idx + 1];
        int j2 = adj_drug[idx + 2], j3 = adj_drug[idx + 3];
        float4 v0 = ((const float4*)(h2 + (size_t)j0 * CDIM))[lane];
        float4 v1 = ((const float4*)(h2 + (size_t)j1 * CDIM))[lane];
        float4 v2 = ((const float4*)(h2 + (size_t)j2 * CDIM))[lane];
        float4 v3 = ((const float4*)(h2 + (size_t)j3 * CDIM))[lane];
        a0.x += v0.x; a0.y += v0.y; a0.z += v0.z; a0.w += v0.w;
        a1.x += v1.x; a1.y += v1.y; a1.z += v1.z; a1.w += v1.w;
        a2.x += v2.x; a2.y += v2.y; a2.z += v2.z; a2.w += v2.w;
        a3.x += v3.x; a3.y += v3.y; a3.z += v3.z; a3.w += v3.w;
    }
    for (; idx < e; idx++) {
        int j = adj_drug[idx];
        float4 v = ((const float4*)(h2 + (size_t)j * CDIM))[lane];
        a0.x += v.x; a0.y += v.y; a0.z += v.z; a0.w += v.w;
    }
    float4 acc;
    acc.x = (a0.x + a1.x) + (a2.x + a3.x);
    acc.y = (a0.y + a1.y) + (a2.y + a3.y);
    acc.z = (a0.z + a1.z) + (a2.z + a3.z);
    acc.w = (a0.w + a1.w) + (a2.w + a3.w);
    int cnt = e - s;
    float sc = 1.f / (float)(cnt > 1 ? cnt : 1);
    acc.x *= sc; acc.y *= sc; acc.z *= sc; acc.w *= sc;
    ushort4 h, l;
    split2(acc.x, h.x, l.x); split2(acc.y, h.y, l.y);
    split2(acc.z, h.z, l.z); split2(acc.w, h.w, l.w);
    *(ushort4*)&Ghi[(size_t)d * CDIM + lane * 4] = h;
    *(ushort4*)&Glo[(size_t)d * CDIM + lane * 4] = l;
}

// ---------------------------------------------------------------------------
// MLP epilogue: out[r] = sum_n relu(H[d0][2c*512+n] + H[d1][(2c+1)*512+n]
//                                   + b1[c][n]) * W2[c][n]  + b2[c]
// one wave per row; coalesced 2KB row reads from L2/L3-resident H; no atomics.
__global__ __launch_bounds__(256) void mlp_out(const float* __restrict__ H,
                                               const int* __restrict__ ddb,
                                               const int* __restrict__ ecl,
                                               const float* __restrict__ b1,
                                               const float* __restrict__ W2,
                                               const float* __restrict__ b2,
                                               float* __restrict__ outp) {
    int r = (blockIdx.x * blockDim.x + threadIdx.x) >> 6;
    int lane = threadIdx.x & 63;
    if (r >= BATCH) return;
    int c = ecl[r];
    int d0 = ddb[r], d1 = ddb[BATCH + r];
    const float* h0 = H + (size_t)d0 * HN + (size_t)(c * 2) * HID;
    const float* h1 = H + (size_t)d1 * HN + (size_t)(c * 2 + 1) * HID;
    const float* b1e = b1 + (size_t)c * HID;
    const float* w2e = W2 + (size_t)c * HID;
    float s = 0.f;
#pragma unroll
    for (int u = 0; u < 2; u++) {
        int n = u * 256 + lane * 4;
        float4 a = *(const float4*)(h0 + n);
        float4 b = *(const float4*)(h1 + n);
        float4 bb = *(const float4*)(b1e + n);
        float4 ww = *(const float4*)(w2e + n);
        s = fmaf(fmaxf(a.x + b.x + bb.x, 0.f), ww.x, s);
        s = fmaf(fmaxf(a.y + b.y + bb.y, 0.f), ww.y, s);
        s = fmaf(fmaxf(a.z + b.z + bb.z, 0.f), ww.z, s);
        s = fmaf(fmaxf(a.w + b.w + bb.w, 0.f), ww.w, s);
    }
    s += __shfl_xor(s, 1);
    s += __shfl_xor(s, 2);
    s += __shfl_xor(s, 4);
    s += __shfl_xor(s, 8);
    s += __shfl_xor(s, 16);
    s += __shfl_xor(s, 32);
    if (lane == 0) outp[r] = s + b2[c];
}

// ---------------------------------------------------------------------------
extern "C" void kernel_launch(void* const* d_in, const int* in_sizes, int n_in,
                              void* d_out, int out_size, void* d_ws, size_t ws_size,
                              hipStream_t stream) {
    const float* x   = (const float*)d_in[0];
    const int* ei    = (const int*)d_in[1];
    const int* ddb   = (const int*)d_in[2];
    const int* ecl   = (const int*)d_in[3];
    const float* Wg1 = (const float*)d_in[5];
    const float* bg1 = (const float*)d_in[6];
    const float* Wg2 = (const float*)d_in[7];
    const float* bg2 = (const float*)d_in[8];
    const float* W1  = (const float*)d_in[9];
    const float* b1  = (const float*)d_in[10];
    const float* W2  = (const float*)d_in[11];
    const float* b2  = (const float*)d_in[12];
    float* outp = (float*)d_out;

    char* p = (char*)d_ws;
    auto alloc = [&](size_t bytes) {
        char* r = p;
        p += (bytes + 255) & ~size_t(255);
        return (void*)r;
    };
    const size_t NC = (size_t)N_NODES * CDIM;
    const size_t HBYTES = (size_t)NUM_DRUGS * HN * sizeof(float);  // 67.1 MB
    // Region 0 = H extent. All pre-H-GEMM scratch lives INSIDE it (sum 66.3 MB
    // <= 67.1 MB) and is dead before the H GEMM writes H. Region 1 (after the
    // H extent) holds buffers the H GEMM reads: Ghi/Glo, W1Th/W1Tl (+ wg*).
    float* H              = (float*)d_ws;
    float* tmp            = (float*)alloc(sizeof(float) * NC);
    unsigned short* h1hi  = (unsigned short*)alloc(2 * NC);
    unsigned short* h1lo  = (unsigned short*)alloc(2 * NC);
    char* xh2_blk         = (char*)alloc(4 * NC);                 // xhi+xlo, later h2
    unsigned short* xhi   = (unsigned short*)xh2_blk;
    unsigned short* xlo   = (unsigned short*)(xh2_blk + 2 * NC);
    float* h2             = (float*)xh2_blk;
    float* dinv    = (float*)alloc(sizeof(float) * N_NODES);
    int* cnt_d     = (int*)alloc(sizeof(int) * NUM_DRUGS * STRD);
    int* cur_d     = (int*)alloc(sizeof(int) * NUM_DRUGS * STRD);
    int* cnt_p     = (int*)alloc(sizeof(int) * N_NODES * STRP);
    int* cur_p     = (int*)alloc(sizeof(int) * N_NODES * STRP);
    int* drug_ptr  = (int*)alloc(sizeof(int) * (NUM_DRUGS + 1));
    int* prot_ptr  = (int*)alloc(sizeof(int) * (N_NODES + 1));
    int* adj_drug  = (int*)alloc(sizeof(int) * NUM_DPI);
    int* adj_prot  = (int*)alloc(sizeof(int) * NUM_DPI);
    // jump to end of H extent for the live (region-1) buffers
    p = (char*)d_ws + ((HBYTES + 255) & ~size_t(255));
    unsigned short* Ghi   = (unsigned short*)alloc(2 * NUM_DRUGS * CDIM);
    unsigned short* Glo   = (unsigned short*)alloc(2 * NUM_DRUGS * CDIM);
    unsigned short* wg1Th = (unsigned short*)alloc(2 * CDIM * CDIM);
    unsigned short* wg1Tl = (unsigned short*)alloc(2 * CDIM * CDIM);
    unsigned short* wg2Th = (unsigned short*)alloc(2 * CDIM * CDIM);
    unsigned short* wg2Tl = (unsigned short*)alloc(2 * CDIM * CDIM);
    unsigned short* W1Th  = (unsigned short*)alloc(2 * (size_t)N_CL * HID * HID);
    unsigned short* W1Tl  = (unsigned short*)alloc(2 * (size_t)N_CL * HID * HID);

    // graph prep
    zero_counts<<<(N_NODES + 255) / 256, 256, 0, stream>>>(cnt_d, cur_d, cnt_p, cur_p);
    count_dpi<<<(NUM_DPI + 255) / 256, 256, 0, stream>>>(ei, cnt_d, cnt_p);
    scan2<<<2, 1024, 0, stream>>>(cnt_d, cnt_p, drug_ptr, prot_ptr);
    fill_dpi<<<(NUM_DPI + 255) / 256, 256, 0, stream>>>(ei, drug_ptr, cur_d, adj_drug,
                                                        prot_ptr, cur_p, adj_prot, dinv);
    // weight/activation splits (coalesced)
    split_mat<<<((int)NC + 255) / 256, 256, 0, stream>>>(x, xhi, xlo, (int)NC);
    transpose_split64<<<dim3(CDIM / 64, CDIM / 64, 1), 256, 0, stream>>>(
        Wg1, wg1Th, wg1Tl, CDIM, CDIM);
    transpose_split64<<<dim3(CDIM / 64, CDIM / 64, 1), 256, 0, stream>>>(
        Wg2, wg2Th, wg2Tl, CDIM, CDIM);
    // W1 [8][512][512] viewed as 16 slabs [256][512] -> W1cat^T [8192][256] split
    transpose_split64<<<dim3(CDIM / 64, HID / 64, 2 * N_CL), 256, 0, stream>>>(
        W1, W1Th, W1Tl, CDIM, HID);
    // GCN layer 1
    gemm_mfma<<<dim3((N_NODES + 127) / 128, CDIM / 128), 256, 0, stream>>>(
        xhi, xlo, wg1Th, wg1Tl, tmp, N_NODES, CDIM, CDIM);
    aggregate_k<<<(N_NODES * 64 + 255) / 256, 256, 0, stream>>>(
        tmp, drug_ptr, adj_drug, prot_ptr, adj_prot, dinv, bg1, nullptr, h1hi, h1lo);
    // GCN layer 2
    gemm_mfma<<<dim3((N_NODES + 127) / 128, CDIM / 128), 256, 0, stream>>>(
        h1hi, h1lo, wg2Th, wg2Tl, tmp, N_NODES, CDIM, CDIM);
    aggregate_k<<<(N_NODES * 64 + 255) / 256, 256, 0, stream>>>(
        tmp, drug_ptr, adj_drug, prot_ptr, adj_prot, dinv, bg2, h2, nullptr, nullptr);
    // pool -> split graph embeddings
    pool_drugs<<<(NUM_DRUGS * 64 + 255) / 256, 256, 0, stream>>>(h2, Ghi, Glo,
                                                                 drug_ptr, adj_drug);
    // MLP precompute: H[2048, 8192] = G @ W1cat  (regular dense GEMM, 1024 blocks)
    gemm_mfma<<<dim3(NUM_DRUGS / 128, HN / 128), 256, 0, stream>>>(
        Ghi, Glo, W1Th, W1Tl, H, NUM_DRUGS, CDIM, HN);
    // epilogue: gather 2 H rows per batch row, relu+dot, direct store
    mlp_out<<<(BATCH * 64) / 256, 256, 0, stream>>>(H, ddb, ecl, b1, W2, b2, outp);
}

// Round 10
// 350.255 us; speedup vs baseline: 1.2725x; 1.1070x over previous
//
#include <hip/hip_runtime.h>
#include <hip/hip_bf16.h>

// Problem constants (fixed by reference)
#define N_NODES 20000
#define NUM_DRUGS 2048
#define N_PROT (N_NODES - NUM_DRUGS)
#define NUM_DPI 200000
#define E2 400000          // 2*NUM_DPI directed edges
#define CDIM 256           // IN_C == EMB == 256
#define HID 512
#define N_CL 8
#define BATCH 16384
#define HN 8192            // H cols = 8 experts x 2 halves x 512

#define STRD 32            // drug counter padding (ints) = 1 line per counter
#define STRP 16            // protein counter padding

typedef __attribute__((ext_vector_type(8))) short short8;   // 8 bf16 (MFMA A/B frag)
typedef __attribute__((ext_vector_type(4))) float floatx4;  // MFMA C/D frag

__device__ inline unsigned short f2bf(float f) {
    unsigned u = __float_as_uint(f);
    u += 0x7fff + ((u >> 16) & 1);   // RNE
    return (unsigned short)(u >> 16);
}
__device__ inline float bf2f(unsigned short h) {
    return __uint_as_float((unsigned)h << 16);
}
__device__ inline void split2(float v, unsigned short& h, unsigned short& l) {
    h = f2bf(v);
    l = f2bf(v - bf2f(h));
}
__device__ inline void gload16(const void* g, void* l) {
    __builtin_amdgcn_global_load_lds(
        (const __attribute__((address_space(1))) void*)g,
        (__attribute__((address_space(3))) void*)l, 16, 0, 0);
}
__device__ inline float4 f4fma(float4 v, float s, float4 a) {
    a.x = fmaf(v.x, s, a.x); a.y = fmaf(v.y, s, a.y);
    a.z = fmaf(v.z, s, a.z); a.w = fmaf(v.w, s, a.w);
    return a;
}
__device__ inline float4 bf4(const unsigned short* p) {
    ushort4 q = *(const ushort4*)p;
    return make_float4(bf2f(q.x), bf2f(q.y), bf2f(q.z), bf2f(q.w));
}

// ---------------------------------------------------------------------------
__global__ void zero_counts(int* cnt_d, int* cur_d, int* cnt_p, int* cur_p) {
    int i = blockIdx.x * blockDim.x + threadIdx.x;
    if (i < N_NODES) { cnt_p[i * STRP] = 0; cur_p[i * STRP] = 0; }
    if (i < NUM_DRUGS) { cnt_d[i * STRD] = 0; cur_d[i * STRD] = 0; }
}

__global__ void count_dpi(const int* __restrict__ ei, int* cnt_d, int* cnt_p) {
    int e = blockIdx.x * blockDim.x + threadIdx.x;
    if (e >= NUM_DPI) return;
    atomicAdd(&cnt_d[ei[e] * STRD], 1);          // drug id of pair e
    atomicAdd(&cnt_p[ei[E2 + e] * STRP], 1);     // protein id of pair e
}

__device__ void scan_dev(const int* counts, int stride, int* ptr, int n) {
    __shared__ int sums[1024];
    int t = threadIdx.x;
    int per = (n + 1023) / 1024;
    int start = t * per;
    int end = start + per; if (end > n) end = n;
    int s = 0;
    for (int i = start; i < end; i++) s += counts[i * stride];
    sums[t] = s;
    __syncthreads();
    for (int off = 1; off < 1024; off <<= 1) {
        int v = (t >= off) ? sums[t - off] : 0;
        __syncthreads();
        sums[t] += v;
        __syncthreads();
    }
    int base = (t == 0) ? 0 : sums[t - 1];
    for (int i = start; i < end; i++) {
        ptr[i] = base;
        base += counts[i * stride];
    }
    if (t == 1023) ptr[n] = sums[1023];
}

__global__ void scan2(const int* cnt_d, const int* cnt_p,
                      int* drug_ptr, int* prot_ptr) {
    if (blockIdx.x == 0) scan_dev(cnt_d, STRD, drug_ptr, NUM_DRUGS);
    else scan_dev(cnt_p, STRP, prot_ptr, N_NODES);
}

__global__ void fill_dpi(const int* __restrict__ ei,
                         const int* __restrict__ drug_ptr, int* cur_d, int* adj_drug,
                         const int* __restrict__ prot_ptr, int* cur_p, int* adj_prot,
                         float* __restrict__ dinv) {
    int e = blockIdx.x * blockDim.x + threadIdx.x;
    if (e < NUM_DPI) {
        int d = ei[e];
        int p = ei[E2 + e];
        int posd = drug_ptr[d] + atomicAdd(&cur_d[d * STRD], 1);
        int posp = prot_ptr[p] + atomicAdd(&cur_p[p * STRP], 1);
        adj_drug[posd] = p;
        adj_prot[posp] = d;
    }
    if (e < N_NODES) {
        int deg = (e < NUM_DRUGS) ? (drug_ptr[e + 1] - drug_ptr[e])
                                  : (prot_ptr[e + 1] - prot_ptr[e]);
        dinv[e] = rsqrtf((float)(deg + 1));
    }
}

// ---------------------------------------------------------------------------
__global__ void split_mat(const float* __restrict__ A, unsigned short* __restrict__ hi,
                          unsigned short* __restrict__ lo, int total) {
    int i = blockIdx.x * blockDim.x + threadIdx.x;
    if (i >= total) return;
    unsigned short h, l;
    split2(A[i], h, l);
    hi[i] = h; lo[i] = l;
}

// LDS-tiled transpose+split: W [m][K][N] fp32 -> [m][N][K] split bf16, coalesced
__global__ __launch_bounds__(256) void transpose_split64(const float* __restrict__ W,
                                                         unsigned short* __restrict__ hi,
                                                         unsigned short* __restrict__ lo,
                                                         int K, int N) {
    __shared__ float ld[64 * 65];
    int m = blockIdx.z;
    int k0 = blockIdx.x * 64, n0 = blockIdx.y * 64;
    const float* Wm = W + (size_t)m * K * N;
    int tx = threadIdx.x & 63, ty = threadIdx.x >> 6;
#pragma unroll
    for (int rr = 0; rr < 16; rr++) {
        int kl = rr * 4 + ty;
        ld[tx * 65 + kl] = Wm[(size_t)(k0 + kl) * N + n0 + tx];
    }
    __syncthreads();
    size_t obase = (size_t)m * N * K;
#pragma unroll
    for (int rr = 0; rr < 16; rr++) {
        int nl = rr * 4 + ty;
        float v = ld[nl * 65 + tx];
        unsigned short h, l;
        split2(v, h, l);
        size_t o = obase + (size_t)(n0 + nl) * K + k0 + tx;
        hi[o] = h;
        lo[o] = l;
    }
}

// ---------------------------------------------------------------------------
// split-bf16 MFMA GEMM: C[M,N] = A[M,K] @ B[K,N], B passed as B^T ([N][K]).
// Row-major XOR-swizzled LDS; optional extra bf16 output copy (Cbf).
__global__ __launch_bounds__(256) void gemm_mfma(
        const unsigned short* __restrict__ Ahi, const unsigned short* __restrict__ Alo,
        const unsigned short* __restrict__ BThi, const unsigned short* __restrict__ BTlo,
        float* __restrict__ C, unsigned short* __restrict__ Cbf,
        int M, int K, int N) {
    __shared__ unsigned short sAh[4096], sAl[4096], sBh[4096], sBl[4096];
    int t = threadIdx.x;
    int wv = t >> 6, lane = t & 63, quad = lane >> 4, l15 = lane & 15;
    int m0 = blockIdx.x * 128, n0 = blockIdx.y * 128;
    int m0w = (wv >> 1) * 64, n0w = (wv & 1) * 64;
    floatx4 zero = {0.f, 0.f, 0.f, 0.f};
    floatx4 acc[4][4];
#pragma unroll
    for (int i = 0; i < 4; i++)
#pragma unroll
        for (int j = 0; j < 4; j++) acc[i][j] = zero;

    for (int kk = 0; kk < K; kk += 32) {
#pragma unroll
        for (int c = 0; c < 2; c++) {
            int s = t + c * 256;                 // slot in [0,512)
            int row = s >> 2, pos = s & 3;
            int ch = pos ^ ((row >> 1) & 3);     // XOR-swizzled chunk
            int arow = m0 + row; if (arow > M - 1) arow = M - 1;
            int brow = n0 + row; if (brow > N - 1) brow = N - 1;
            size_t aoff = (size_t)arow * K + kk + ch * 8;
            size_t boff = (size_t)brow * K + kk + ch * 8;
            gload16(Ahi + aoff, &sAh[s * 8]);
            gload16(Alo + aoff, &sAl[s * 8]);
            gload16(BThi + boff, &sBh[s * 8]);
            gload16(BTlo + boff, &sBl[s * 8]);
        }
        __syncthreads();
        short8 ah[4], al[4], bh[4], bl[4];
        int posq = quad ^ ((l15 >> 1) & 3);
#pragma unroll
        for (int i = 0; i < 4; i++) {
            int sl = (m0w + i * 16 + l15) * 4 + posq;
            ah[i] = *(const short8*)&sAh[sl * 8];
            al[i] = *(const short8*)&sAl[sl * 8];
        }
#pragma unroll
        for (int j = 0; j < 4; j++) {
            int sl = (n0w + j * 16 + l15) * 4 + posq;
            bh[j] = *(const short8*)&sBh[sl * 8];
            bl[j] = *(const short8*)&sBl[sl * 8];
        }
#pragma unroll
        for (int i = 0; i < 4; i++)
#pragma unroll
            for (int j = 0; j < 4; j++) {
                acc[i][j] = __builtin_amdgcn_mfma_f32_16x16x32_bf16(ah[i], bh[j], acc[i][j], 0, 0, 0);
                acc[i][j] = __builtin_amdgcn_mfma_f32_16x16x32_bf16(ah[i], bl[j], acc[i][j], 0, 0, 0);
                acc[i][j] = __builtin_amdgcn_mfma_f32_16x16x32_bf16(al[i], bh[j], acc[i][j], 0, 0, 0);
            }
        __syncthreads();
    }
#pragma unroll
    for (int i = 0; i < 4; i++) {
        int gr = m0 + m0w + i * 16 + quad * 4;
#pragma unroll
        for (int r = 0; r < 4; r++) {
            if (gr + r < M) {
#pragma unroll
                for (int j = 0; j < 4; j++) {
                    size_t o = (size_t)(gr + r) * N + n0 + n0w + j * 16 + l15;
                    float v = acc[i][j][r];
                    C[o] = v;
                    if (Cbf) Cbf[o] = f2bf(v);
                }
            }
        }
    }
}

// ---------------------------------------------------------------------------
// Layer-1 GCN aggregate. Drug destinations gather protein rows in bf16 (halved
// traffic, 2x L2 hit); protein destinations gather drug rows fp32 (2MB set,
// L2-resident). Output: split-bf16 h1.
__global__ __launch_bounds__(256) void aggregate1(const float* __restrict__ tmp,
                                                  const unsigned short* __restrict__ tmpbf,
                                                  const int* __restrict__ drug_ptr,
                                                  const int* __restrict__ adj_drug,
                                                  const int* __restrict__ prot_ptr,
                                                  const int* __restrict__ adj_prot,
                                                  const float* __restrict__ dinv,
                                                  const float* __restrict__ bias,
                                                  unsigned short* __restrict__ outhi,
                                                  unsigned short* __restrict__ outlo) {
    int i = (blockIdx.x * blockDim.x + threadIdx.x) >> 6;
    int lane = threadIdx.x & 63;
    if (i >= N_NODES) return;
    float di = dinv[i];
    float4 a0 = make_float4(0.f, 0.f, 0.f, 0.f);
    float4 a1 = a0, a2 = a0, a3 = a0;
    if (i < NUM_DRUGS) {
        int s = drug_ptr[i], e = drug_ptr[i + 1];
        int idx = s;
        for (; idx + 4 <= e; idx += 4) {
            int j0 = adj_drug[idx + 0], j1 = adj_drug[idx + 1];
            int j2 = adj_drug[idx + 2], j3 = adj_drug[idx + 3];
            float d0 = dinv[j0], d1 = dinv[j1], d2 = dinv[j2], d3 = dinv[j3];
            float4 v0 = bf4(&tmpbf[(size_t)j0 * CDIM + lane * 4]);
            float4 v1 = bf4(&tmpbf[(size_t)j1 * CDIM + lane * 4]);
            float4 v2 = bf4(&tmpbf[(size_t)j2 * CDIM + lane * 4]);
            float4 v3 = bf4(&tmpbf[(size_t)j3 * CDIM + lane * 4]);
            a0 = f4fma(v0, d0, a0);
            a1 = f4fma(v1, d1, a1);
            a2 = f4fma(v2, d2, a2);
            a3 = f4fma(v3, d3, a3);
        }
        for (; idx < e; idx++) {
            int j = adj_drug[idx];
            a0 = f4fma(bf4(&tmpbf[(size_t)j * CDIM + lane * 4]), dinv[j], a0);
        }
    } else {
        int s = prot_ptr[i], e = prot_ptr[i + 1];
        int idx = s;
        for (; idx + 4 <= e; idx += 4) {
            int j0 = adj_prot[idx + 0], j1 = adj_prot[idx + 1];
            int j2 = adj_prot[idx + 2], j3 = adj_prot[idx + 3];
            float d0 = dinv[j0], d1 = dinv[j1], d2 = dinv[j2], d3 = dinv[j3];
            float4 v0 = ((const float4*)(tmp + (size_t)j0 * CDIM))[lane];
            float4 v1 = ((const float4*)(tmp + (size_t)j1 * CDIM))[lane];
            float4 v2 = ((const float4*)(tmp + (size_t)j2 * CDIM))[lane];
            float4 v3 = ((const float4*)(tmp + (size_t)j3 * CDIM))[lane];
            a0 = f4fma(v0, d0, a0);
            a1 = f4fma(v1, d1, a1);
            a2 = f4fma(v2, d2, a2);
            a3 = f4fma(v3, d3, a3);
        }
        for (; idx < e; idx++) {
            int j = adj_prot[idx];
            a0 = f4fma(((const float4*)(tmp + (size_t)j * CDIM))[lane], dinv[j], a0);
        }
    }
    float4 self = ((const float4*)(tmp + (size_t)i * CDIM))[lane];
    float4 acc;
    acc.x = (a0.x + a1.x) + (a2.x + a3.x) + self.x * di;
    acc.y = (a0.y + a1.y) + (a2.y + a3.y) + self.y * di;
    acc.z = (a0.z + a1.z) + (a2.z + a3.z) + self.z * di;
    acc.w = (a0.w + a1.w) + (a2.w + a3.w) + self.w * di;
    float4 bv = ((const float4*)bias)[lane];
    float4 r;
    r.x = fmaxf(fmaf(acc.x, di, bv.x), 0.f);
    r.y = fmaxf(fmaf(acc.y, di, bv.y), 0.f);
    r.z = fmaxf(fmaf(acc.z, di, bv.z), 0.f);
    r.w = fmaxf(fmaf(acc.w, di, bv.w), 0.f);
    ushort4 h, l;
    split2(r.x, h.x, l.x); split2(r.y, h.y, l.y);
    split2(r.z, h.z, l.z); split2(r.w, h.w, l.w);
    *(ushort4*)&outhi[(size_t)i * CDIM + lane * 4] = h;
    *(ushort4*)&outlo[(size_t)i * CDIM + lane * 4] = l;
}

// Layer-2 GCN aggregate, PROTEIN rows only (drug h2 rows are dead — pool never
// reads them). Gathers drug rows fp32 (2MB, L2-resident); emits bf16 h2.
__global__ __launch_bounds__(256) void aggregate2p(const float* __restrict__ tmp2,
                                                   const int* __restrict__ prot_ptr,
                                                   const int* __restrict__ adj_prot,
                                                   const float* __restrict__ dinv,
                                                   const float* __restrict__ bias,
                                                   unsigned short* __restrict__ h2bf) {
    int w = (blockIdx.x * blockDim.x + threadIdx.x) >> 6;
    int lane = threadIdx.x & 63;
    if (w >= N_PROT) return;
    int i = NUM_DRUGS + w;
    float di = dinv[i];
    float4 a0 = make_float4(0.f, 0.f, 0.f, 0.f);
    float4 a1 = a0, a2 = a0, a3 = a0;
    int s = prot_ptr[i], e = prot_ptr[i + 1];
    int idx = s;
    for (; idx + 4 <= e; idx += 4) {
        int j0 = adj_prot[idx + 0], j1 = adj_prot[idx + 1];
        int j2 = adj_prot[idx + 2], j3 = adj_prot[idx + 3];
        float d0 = dinv[j0], d1 = dinv[j1], d2 = dinv[j2], d3 = dinv[j3];
        float4 v0 = ((const float4*)(tmp2 + (size_t)j0 * CDIM))[lane];
        float4 v1 = ((const float4*)(tmp2 + (size_t)j1 * CDIM))[lane];
        float4 v2 = ((const float4*)(tmp2 + (size_t)j2 * CDIM))[lane];
        float4 v3 = ((const float4*)(tmp2 + (size_t)j3 * CDIM))[lane];
        a0 = f4fma(v0, d0, a0);
        a1 = f4fma(v1, d1, a1);
        a2 = f4fma(v2, d2, a2);
        a3 = f4fma(v3, d3, a3);
    }
    for (; idx < e; idx++) {
        int j = adj_prot[idx];
        a0 = f4fma(((const float4*)(tmp2 + (size_t)j * CDIM))[lane], dinv[j], a0);
    }
    float4 self = ((const float4*)(tmp2 + (size_t)i * CDIM))[lane];
    float4 acc;
    acc.x = (a0.x + a1.x) + (a2.x + a3.x) + self.x * di;
    acc.y = (a0.y + a1.y) + (a2.y + a3.y) + self.y * di;
    acc.z = (a0.z + a1.z) + (a2.z + a3.z) + self.z * di;
    acc.w = (a0.w + a1.w) + (a2.w + a3.w) + self.w * di;
    float4 bv = ((const float4*)bias)[lane];
    ushort4 o;
    o.x = f2bf(fmaxf(fmaf(acc.x, di, bv.x), 0.f));
    o.y = f2bf(fmaxf(fmaf(acc.y, di, bv.y), 0.f));
    o.z = f2bf(fmaxf(fmaf(acc.z, di, bv.z), 0.f));
    o.w = f2bf(fmaxf(fmaf(acc.w, di, bv.w), 0.f));
    *(ushort4*)&h2bf[(size_t)i * CDIM + lane * 4] = o;
}

// scatter-mean pool from bf16 h2 -> split-bf16 graph embeddings; 4-way unrolled
__global__ __launch_bounds__(256) void pool_drugs(const unsigned short* __restrict__ h2bf,
                                                  unsigned short* __restrict__ Ghi,
                                                  unsigned short* __restrict__ Glo,
                                                  const int* __restrict__ drug_ptr,
                                                  const int* __restrict__ adj_drug) {
    int d = (blockIdx.x * blockDim.x + threadIdx.x) >> 6;
    int lane = threadIdx.x & 63;
    if (d >= NUM_DRUGS) return;
    int s = drug_ptr[d], e = drug_ptr[d + 1];
    float4 a0 = make_float4(0.f, 0.f, 0.f, 0.f);
    float4 a1 = a0, a2 = a0, a3 = a0;
    int idx = s;
    for (; idx + 4 <= e; idx += 4) {
        int j0 = adj_drug[idx + 0], j1 = adj_drug[idx + 1];
        int j2 = adj_drug[idx + 2], j3 = adj_drug[idx + 3];
        float4 v0 = bf4(&h2bf[(size_t)j0 * CDIM + lane * 4]);
        float4 v1 = bf4(&h2bf[(size_t)j1 * CDIM + lane * 4]);
        float4 v2 = bf4(&h2bf[(size_t)j2 * CDIM + lane * 4]);
        float4 v3 = bf4(&h2bf[(size_t)j3 * CDIM + lane * 4]);
        a0.x += v0.x; a0.y += v0.y; a0.z += v0.z; a0.w += v0.w;
        a1.x += v1.x; a1.y += v1.y; a1.z += v1.z; a1.w += v1.w;
        a2.x += v2.x; a2.y += v2.y; a2.z += v2.z; a2.w += v2.w;
        a3.x += v3.x; a3.y += v3.y; a3.z += v3.z; a3.w += v3.w;
    }
    for (; idx < e; idx++) {
        int j = adj_drug[idx];
        float4 v = bf4(&h2bf[(size_t)j * CDIM + lane * 4]);
        a0.x += v.x; a0.y += v.y; a0.z += v.z; a0.w += v.w;
    }
    float4 acc;
    acc.x = (a0.x + a1.x) + (a2.x + a3.x);
    acc.y = (a0.y + a1.y) + (a2.y + a3.y);
    acc.z = (a0.z + a1.z) + (a2.z + a3.z);
    acc.w = (a0.w + a1.w) + (a2.w + a3.w);
    int cnt = e - s;
    float sc = 1.f / (float)(cnt > 1 ? cnt : 1);
    acc.x *= sc; acc.y *= sc; acc.z *= sc; acc.w *= sc;
    ushort4 h, l;
    split2(acc.x, h.x, l.x); split2(acc.y, h.y, l.y);
    split2(acc.z, h.z, l.z); split2(acc.w, h.w, l.w);
    *(ushort4*)&Ghi[(size_t)d * CDIM + lane * 4] = h;
    *(ushort4*)&Glo[(size_t)d * CDIM + lane * 4] = l;
}

// ---------------------------------------------------------------------------
// MLP epilogue (unchanged): gather 2 H rows, relu+dot W2, direct store
__global__ __launch_bounds__(256) void mlp_out(const float* __restrict__ H,
                                               const int* __restrict__ ddb,
                                               const int* __restrict__ ecl,
                                               const float* __restrict__ b1,
                                               const float* __restrict__ W2,
                                               const float* __restrict__ b2,
                                               float* __restrict__ outp) {
    int r = (blockIdx.x * blockDim.x + threadIdx.x) >> 6;
    int lane = threadIdx.x & 63;
    if (r >= BATCH) return;
    int c = ecl[r];
    int d0 = ddb[r], d1 = ddb[BATCH + r];
    const float* h0 = H + (size_t)d0 * HN + (size_t)(c * 2) * HID;
    const float* h1 = H + (size_t)d1 * HN + (size_t)(c * 2 + 1) * HID;
    const float* b1e = b1 + (size_t)c * HID;
    const float* w2e = W2 + (size_t)c * HID;
    float s = 0.f;
#pragma unroll
    for (int u = 0; u < 2; u++) {
        int n = u * 256 + lane * 4;
        float4 a = *(const float4*)(h0 + n);
        float4 b = *(const float4*)(h1 + n);
        float4 bb = *(const float4*)(b1e + n);
        float4 ww = *(const float4*)(w2e + n);
        s = fmaf(fmaxf(a.x + b.x + bb.x, 0.f), ww.x, s);
        s = fmaf(fmaxf(a.y + b.y + bb.y, 0.f), ww.y, s);
        s = fmaf(fmaxf(a.z + b.z + bb.z, 0.f), ww.z, s);
        s = fmaf(fmaxf(a.w + b.w + bb.w, 0.f), ww.w, s);
    }
    s += __shfl_xor(s, 1);
    s += __shfl_xor(s, 2);
    s += __shfl_xor(s, 4);
    s += __shfl_xor(s, 8);
    s += __shfl_xor(s, 16);
    s += __shfl_xor(s, 32);
    if (lane == 0) outp[r] = s + b2[c];
}

// ---------------------------------------------------------------------------
extern "C" void kernel_launch(void* const* d_in, const int* in_sizes, int n_in,
                              void* d_out, int out_size, void* d_ws, size_t ws_size,
                              hipStream_t stream) {
    const float* x   = (const float*)d_in[0];
    const int* ei    = (const int*)d_in[1];
    const int* ddb   = (const int*)d_in[2];
    const int* ecl   = (const int*)d_in[3];
    const float* Wg1 = (const float*)d_in[5];
    const float* bg1 = (const float*)d_in[6];
    const float* Wg2 = (const float*)d_in[7];
    const float* bg2 = (const float*)d_in[8];
    const float* W1  = (const float*)d_in[9];
    const float* b1  = (const float*)d_in[10];
    const float* W2  = (const float*)d_in[11];
    const float* b2  = (const float*)d_in[12];
    float* outp = (float*)d_out;

    const size_t NC = (size_t)N_NODES * CDIM;                      // 5.12M elems
    const size_t HBYTES = (size_t)NUM_DRUGS * HN * sizeof(float);  // 67.1 MB
    // Region 0 (inside H extent, all dead before the H GEMM writes H):
    //   [0, 20.48M)       tmp  (fp32 GEMM out; reused as tmp2)
    //   [20.48M, 30.72M)  t1bf (bf16 copy of tmp1); reused as h2bf after agg1
    //   [30.72M, 40.96M)  h1hi; aliased by xhi before agg1
    //   [40.96M, 51.20M)  h1lo; aliased by xlo before agg1
    //   [51.20M, ~56M)    counters/adj (live through pool, dead before H GEMM)
    char* r0 = (char*)d_ws;
    float* H              = (float*)d_ws;
    float* tmp            = (float*)r0;
    unsigned short* t1bf  = (unsigned short*)(r0 + 20480000);
    unsigned short* h2bf  = t1bf;
    unsigned short* h1hi  = (unsigned short*)(r0 + 30720000);
    unsigned short* h1lo  = (unsigned short*)(r0 + 40960000);
    unsigned short* xhi   = h1hi;
    unsigned short* xlo   = h1lo;
    char* p = r0 + 51200000;
    auto alloc = [&](size_t bytes) {
        char* r = p;
        p += (bytes + 255) & ~size_t(255);
        return (void*)r;
    };
    float* dinv    = (float*)alloc(sizeof(float) * N_NODES);
    int* cnt_d     = (int*)alloc(sizeof(int) * NUM_DRUGS * STRD);
    int* cur_d     = (int*)alloc(sizeof(int) * NUM_DRUGS * STRD);
    int* cnt_p     = (int*)alloc(sizeof(int) * N_NODES * STRP);
    int* cur_p     = (int*)alloc(sizeof(int) * N_NODES * STRP);
    int* drug_ptr  = (int*)alloc(sizeof(int) * (NUM_DRUGS + 1));
    int* prot_ptr  = (int*)alloc(sizeof(int) * (N_NODES + 1));
    int* adj_drug  = (int*)alloc(sizeof(int) * NUM_DPI);
    int* adj_prot  = (int*)alloc(sizeof(int) * NUM_DPI);
    // Region 1 (after H extent): buffers the H GEMM reads
    p = (char*)d_ws + ((HBYTES + 255) & ~size_t(255));
    unsigned short* Ghi   = (unsigned short*)alloc(2 * NUM_DRUGS * CDIM);
    unsigned short* Glo   = (unsigned short*)alloc(2 * NUM_DRUGS * CDIM);
    unsigned short* wg1Th = (unsigned short*)alloc(2 * CDIM * CDIM);
    unsigned short* wg1Tl = (unsigned short*)alloc(2 * CDIM * CDIM);
    unsigned short* wg2Th = (unsigned short*)alloc(2 * CDIM * CDIM);
    unsigned short* wg2Tl = (unsigned short*)alloc(2 * CDIM * CDIM);
    unsigned short* W1Th  = (unsigned short*)alloc(2 * (size_t)N_CL * HID * HID);
    unsigned short* W1Tl  = (unsigned short*)alloc(2 * (size_t)N_CL * HID * HID);

    // graph prep
    zero_counts<<<(N_NODES + 255) / 256, 256, 0, stream>>>(cnt_d, cur_d, cnt_p, cur_p);
    count_dpi<<<(NUM_DPI + 255) / 256, 256, 0, stream>>>(ei, cnt_d, cnt_p);
    scan2<<<2, 1024, 0, stream>>>(cnt_d, cnt_p, drug_ptr, prot_ptr);
    fill_dpi<<<(NUM_DPI + 255) / 256, 256, 0, stream>>>(ei, drug_ptr, cur_d, adj_drug,
                                                        prot_ptr, cur_p, adj_prot, dinv);
    // weight/activation splits (coalesced)
    split_mat<<<((int)NC + 255) / 256, 256, 0, stream>>>(x, xhi, xlo, (int)NC);
    transpose_split64<<<dim3(CDIM / 64, CDIM / 64, 1), 256, 0, stream>>>(
        Wg1, wg1Th, wg1Tl, CDIM, CDIM);
    transpose_split64<<<dim3(CDIM / 64, CDIM / 64, 1), 256, 0, stream>>>(
        Wg2, wg2Th, wg2Tl, CDIM, CDIM);
    // W1 [8][512][512] viewed as 16 slabs [256][512] -> W1cat^T [8192][256] split
    transpose_split64<<<dim3(CDIM / 64, HID / 64, 2 * N_CL), 256, 0, stream>>>(
        W1, W1Th, W1Tl, CDIM, HID);
    // GCN layer 1 (GEMM also emits bf16 copy for the drug-side gather)
    gemm_mfma<<<dim3((N_NODES + 127) / 128, CDIM / 128), 256, 0, stream>>>(
        xhi, xlo, wg1Th, wg1Tl, tmp, t1bf, N_NODES, CDIM, CDIM);
    aggregate1<<<(N_NODES * 64 + 255) / 256, 256, 0, stream>>>(
        tmp, t1bf, drug_ptr, adj_drug, prot_ptr, adj_prot, dinv, bg1, h1hi, h1lo);
    // GCN layer 2 (protein rows only downstream)
    gemm_mfma<<<dim3((N_NODES + 127) / 128, CDIM / 128), 256, 0, stream>>>(
        h1hi, h1lo, wg2Th, wg2Tl, tmp, nullptr, N_NODES, CDIM, CDIM);
    aggregate2p<<<(N_PROT * 64 + 255) / 256, 256, 0, stream>>>(
        tmp, prot_ptr, adj_prot, dinv, bg2, h2bf);
    // pool (bf16 gather) -> split graph embeddings
    pool_drugs<<<(NUM_DRUGS * 64 + 255) / 256, 256, 0, stream>>>(h2bf, Ghi, Glo,
                                                                 drug_ptr, adj_drug);
    // MLP precompute: H[2048, 8192] = G @ W1cat (regular dense GEMM)
    gemm_mfma<<<dim3(NUM_DRUGS / 128, HN / 128), 256, 0, stream>>>(
        Ghi, Glo, W1Th, W1Tl, H, nullptr, NUM_DRUGS, CDIM, HN);
    // epilogue: gather 2 H rows per batch row, relu+dot, direct store
    mlp_out<<<(BATCH * 64) / 256, 256, 0, stream>>>(H, ddb, ecl, b1, W2, b2, outp);
}

// Round 11
// 290.150 us; speedup vs baseline: 1.5361x; 1.2072x over previous
//
#include <hip/hip_runtime.h>
#include <hip/hip_bf16.h>

// Problem constants (fixed by reference)
#define N_NODES 20000
#define NUM_DRUGS 2048
#define N_PROT (N_NODES - NUM_DRUGS)
#define NUM_DPI 200000
#define E2 400000          // 2*NUM_DPI directed edges
#define CDIM 256           // IN_C == EMB == 256
#define HID 512
#define N_CL 8
#define BATCH 16384
#define HN 8192            // H cols = 8 experts x 2 halves x 512

#define STRD 32            // drug counter padding (ints) = 1 line per counter
#define STRP 16            // protein counter padding
#define ELLD 192           // drug ELL stride (mean deg 97.7, +9.5 sigma)
#define ELLP 48            // protein ELL stride (mean deg 11.1, +11 sigma)

typedef __attribute__((ext_vector_type(8))) short short8;   // 8 bf16 (MFMA A/B frag)
typedef __attribute__((ext_vector_type(4))) float floatx4;  // MFMA C/D frag

__device__ inline unsigned short f2bf(float f) {
    unsigned u = __float_as_uint(f);
    u += 0x7fff + ((u >> 16) & 1);   // RNE
    return (unsigned short)(u >> 16);
}
__device__ inline float bf2f(unsigned short h) {
    return __uint_as_float((unsigned)h << 16);
}
__device__ inline void split2(float v, unsigned short& h, unsigned short& l) {
    h = f2bf(v);
    l = f2bf(v - bf2f(h));
}
__device__ inline void gload16(const void* g, void* l) {
    __builtin_amdgcn_global_load_lds(
        (const __attribute__((address_space(1))) void*)g,
        (__attribute__((address_space(3))) void*)l, 16, 0, 0);
}
__device__ inline float4 f4fma(float4 v, float s, float4 a) {
    a.x = fmaf(v.x, s, a.x); a.y = fmaf(v.y, s, a.y);
    a.z = fmaf(v.z, s, a.z); a.w = fmaf(v.w, s, a.w);
    return a;
}
__device__ inline float4 bf4(const unsigned short* p) {
    ushort4 q = *(const ushort4*)p;
    return make_float4(bf2f(q.x), bf2f(q.y), bf2f(q.z), bf2f(q.w));
}

// ---------------------------------------------------------------------------
__global__ void zero_counts(int* cur_d, int* cur_p) {
    int i = blockIdx.x * blockDim.x + threadIdx.x;
    if (i < N_NODES) cur_p[i * STRP] = 0;
    if (i < NUM_DRUGS) cur_d[i * STRD] = 0;
}

// fill both ELL adjacency lists directly (no count/scan passes needed)
__global__ void fill_ell(const int* __restrict__ ei, int* cur_d, int* adj_drug,
                         int* cur_p, int* adj_prot) {
    int e = blockIdx.x * blockDim.x + threadIdx.x;
    if (e >= NUM_DPI) return;
    int d = ei[e];
    int p = ei[E2 + e];
    int posd = atomicAdd(&cur_d[d * STRD], 1);
    int posp = atomicAdd(&cur_p[p * STRP], 1);
    if (posd < ELLD) adj_drug[d * ELLD + posd] = p;   // clamp: never corrupt neighbor
    if (posp < ELLP) adj_prot[(size_t)p * ELLP + posp] = d;
}

// dinv from final cursor values (deg + 1 self-loop)
__global__ void calc_dinv(const int* __restrict__ cur_d, const int* __restrict__ cur_p,
                          float* __restrict__ dinv) {
    int i = blockIdx.x * blockDim.x + threadIdx.x;
    if (i >= N_NODES) return;
    int deg = (i < NUM_DRUGS) ? cur_d[i * STRD] : cur_p[i * STRP];
    dinv[i] = rsqrtf((float)(deg + 1));
}

// ---------------------------------------------------------------------------
__global__ void split_mat(const float* __restrict__ A, unsigned short* __restrict__ hi,
                          unsigned short* __restrict__ lo, int total) {
    int i = blockIdx.x * blockDim.x + threadIdx.x;
    if (i >= total) return;
    unsigned short h, l;
    split2(A[i], h, l);
    hi[i] = h; lo[i] = l;
}

// LDS-tiled transpose+split: W [m][K][N] fp32 -> [m][N][K] split bf16, coalesced
__global__ __launch_bounds__(256) void transpose_split64(const float* __restrict__ W,
                                                         unsigned short* __restrict__ hi,
                                                         unsigned short* __restrict__ lo,
                                                         int K, int N) {
    __shared__ float ld[64 * 65];
    int m = blockIdx.z;
    int k0 = blockIdx.x * 64, n0 = blockIdx.y * 64;
    const float* Wm = W + (size_t)m * K * N;
    int tx = threadIdx.x & 63, ty = threadIdx.x >> 6;
#pragma unroll
    for (int rr = 0; rr < 16; rr++) {
        int kl = rr * 4 + ty;
        ld[tx * 65 + kl] = Wm[(size_t)(k0 + kl) * N + n0 + tx];
    }
    __syncthreads();
    size_t obase = (size_t)m * N * K;
#pragma unroll
    for (int rr = 0; rr < 16; rr++) {
        int nl = rr * 4 + ty;
        float v = ld[nl * 65 + tx];
        unsigned short h, l;
        split2(v, h, l);
        size_t o = obase + (size_t)(n0 + nl) * K + k0 + tx;
        hi[o] = h;
        lo[o] = l;
    }
}

// ---------------------------------------------------------------------------
// split-bf16 MFMA GEMM: C[M,N] = A[M,K] @ B[K,N], B passed as B^T ([N][K]).
// Row-major XOR-swizzled LDS; optional extra bf16 output copy (Cbf).
__global__ __launch_bounds__(256) void gemm_mfma(
        const unsigned short* __restrict__ Ahi, const unsigned short* __restrict__ Alo,
        const unsigned short* __restrict__ BThi, const unsigned short* __restrict__ BTlo,
        float* __restrict__ C, unsigned short* __restrict__ Cbf,
        int M, int K, int N) {
    __shared__ unsigned short sAh[4096], sAl[4096], sBh[4096], sBl[4096];
    int t = threadIdx.x;
    int wv = t >> 6, lane = t & 63, quad = lane >> 4, l15 = lane & 15;
    int m0 = blockIdx.x * 128, n0 = blockIdx.y * 128;
    int m0w = (wv >> 1) * 64, n0w = (wv & 1) * 64;
    floatx4 zero = {0.f, 0.f, 0.f, 0.f};
    floatx4 acc[4][4];
#pragma unroll
    for (int i = 0; i < 4; i++)
#pragma unroll
        for (int j = 0; j < 4; j++) acc[i][j] = zero;

    for (int kk = 0; kk < K; kk += 32) {
#pragma unroll
        for (int c = 0; c < 2; c++) {
            int s = t + c * 256;                 // slot in [0,512)
            int row = s >> 2, pos = s & 3;
            int ch = pos ^ ((row >> 1) & 3);     // XOR-swizzled chunk
            int arow = m0 + row; if (arow > M - 1) arow = M - 1;
            int brow = n0 + row; if (brow > N - 1) brow = N - 1;
            size_t aoff = (size_t)arow * K + kk + ch * 8;
            size_t boff = (size_t)brow * K + kk + ch * 8;
            gload16(Ahi + aoff, &sAh[s * 8]);
            gload16(Alo + aoff, &sAl[s * 8]);
            gload16(BThi + boff, &sBh[s * 8]);
            gload16(BTlo + boff, &sBl[s * 8]);
        }
        __syncthreads();
        short8 ah[4], al[4], bh[4], bl[4];
        int posq = quad ^ ((l15 >> 1) & 3);
#pragma unroll
        for (int i = 0; i < 4; i++) {
            int sl = (m0w + i * 16 + l15) * 4 + posq;
            ah[i] = *(const short8*)&sAh[sl * 8];
            al[i] = *(const short8*)&sAl[sl * 8];
        }
#pragma unroll
        for (int j = 0; j < 4; j++) {
            int sl = (n0w + j * 16 + l15) * 4 + posq;
            bh[j] = *(const short8*)&sBh[sl * 8];
            bl[j] = *(const short8*)&sBl[sl * 8];
        }
#pragma unroll
        for (int i = 0; i < 4; i++)
#pragma unroll
            for (int j = 0; j < 4; j++) {
                acc[i][j] = __builtin_amdgcn_mfma_f32_16x16x32_bf16(ah[i], bh[j], acc[i][j], 0, 0, 0);
                acc[i][j] = __builtin_amdgcn_mfma_f32_16x16x32_bf16(ah[i], bl[j], acc[i][j], 0, 0, 0);
                acc[i][j] = __builtin_amdgcn_mfma_f32_16x16x32_bf16(al[i], bh[j], acc[i][j], 0, 0, 0);
            }
        __syncthreads();
    }
#pragma unroll
    for (int i = 0; i < 4; i++) {
        int gr = m0 + m0w + i * 16 + quad * 4;
#pragma unroll
        for (int r = 0; r < 4; r++) {
            if (gr + r < M) {
#pragma unroll
                for (int j = 0; j < 4; j++) {
                    size_t o = (size_t)(gr + r) * N + n0 + n0w + j * 16 + l15;
                    float v = acc[i][j][r];
                    C[o] = v;
                    if (Cbf) Cbf[o] = f2bf(v);
                }
            }
        }
    }
}

// ---------------------------------------------------------------------------
// Layer-1 GCN aggregate over ELL lists. Drug destinations gather protein rows
// bf16 (halved traffic); protein destinations gather drug rows fp32 (L2-res).
__global__ __launch_bounds__(256) void aggregate1(const float* __restrict__ tmp,
                                                  const unsigned short* __restrict__ tmpbf,
                                                  const int* __restrict__ cur_d,
                                                  const int* __restrict__ adj_drug,
                                                  const int* __restrict__ cur_p,
                                                  const int* __restrict__ adj_prot,
                                                  const float* __restrict__ dinv,
                                                  const float* __restrict__ bias,
                                                  unsigned short* __restrict__ outhi,
                                                  unsigned short* __restrict__ outlo) {
    int i = (blockIdx.x * blockDim.x + threadIdx.x) >> 6;
    int lane = threadIdx.x & 63;
    if (i >= N_NODES) return;
    float di = dinv[i];
    float4 a0 = make_float4(0.f, 0.f, 0.f, 0.f);
    float4 a1 = a0, a2 = a0, a3 = a0;
    if (i < NUM_DRUGS) {
        const int* adj = adj_drug + (size_t)i * ELLD;
        int e = cur_d[i * STRD];
        int idx = 0;
        for (; idx + 4 <= e; idx += 4) {
            int j0 = adj[idx + 0], j1 = adj[idx + 1];
            int j2 = adj[idx + 2], j3 = adj[idx + 3];
            float d0 = dinv[j0], d1 = dinv[j1], d2 = dinv[j2], d3 = dinv[j3];
            float4 v0 = bf4(&tmpbf[(size_t)j0 * CDIM + lane * 4]);
            float4 v1 = bf4(&tmpbf[(size_t)j1 * CDIM + lane * 4]);
            float4 v2 = bf4(&tmpbf[(size_t)j2 * CDIM + lane * 4]);
            float4 v3 = bf4(&tmpbf[(size_t)j3 * CDIM + lane * 4]);
            a0 = f4fma(v0, d0, a0);
            a1 = f4fma(v1, d1, a1);
            a2 = f4fma(v2, d2, a2);
            a3 = f4fma(v3, d3, a3);
        }
        for (; idx < e; idx++) {
            int j = adj[idx];
            a0 = f4fma(bf4(&tmpbf[(size_t)j * CDIM + lane * 4]), dinv[j], a0);
        }
    } else {
        const int* adj = adj_prot + (size_t)i * ELLP;
        int e = cur_p[i * STRP];
        int idx = 0;
        for (; idx + 4 <= e; idx += 4) {
            int j0 = adj[idx + 0], j1 = adj[idx + 1];
            int j2 = adj[idx + 2], j3 = adj[idx + 3];
            float d0 = dinv[j0], d1 = dinv[j1], d2 = dinv[j2], d3 = dinv[j3];
            float4 v0 = ((const float4*)(tmp + (size_t)j0 * CDIM))[lane];
            float4 v1 = ((const float4*)(tmp + (size_t)j1 * CDIM))[lane];
            float4 v2 = ((const float4*)(tmp + (size_t)j2 * CDIM))[lane];
            float4 v3 = ((const float4*)(tmp + (size_t)j3 * CDIM))[lane];
            a0 = f4fma(v0, d0, a0);
            a1 = f4fma(v1, d1, a1);
            a2 = f4fma(v2, d2, a2);
            a3 = f4fma(v3, d3, a3);
        }
        for (; idx < e; idx++) {
            int j = adj[idx];
            a0 = f4fma(((const float4*)(tmp + (size_t)j * CDIM))[lane], dinv[j], a0);
        }
    }
    float4 self = ((const float4*)(tmp + (size_t)i * CDIM))[lane];
    float4 acc;
    acc.x = (a0.x + a1.x) + (a2.x + a3.x) + self.x * di;
    acc.y = (a0.y + a1.y) + (a2.y + a3.y) + self.y * di;
    acc.z = (a0.z + a1.z) + (a2.z + a3.z) + self.z * di;
    acc.w = (a0.w + a1.w) + (a2.w + a3.w) + self.w * di;
    float4 bv = ((const float4*)bias)[lane];
    float4 r;
    r.x = fmaxf(fmaf(acc.x, di, bv.x), 0.f);
    r.y = fmaxf(fmaf(acc.y, di, bv.y), 0.f);
    r.z = fmaxf(fmaf(acc.z, di, bv.z), 0.f);
    r.w = fmaxf(fmaf(acc.w, di, bv.w), 0.f);
    ushort4 h, l;
    split2(r.x, h.x, l.x); split2(r.y, h.y, l.y);
    split2(r.z, h.z, l.z); split2(r.w, h.w, l.w);
    *(ushort4*)&outhi[(size_t)i * CDIM + lane * 4] = h;
    *(ushort4*)&outlo[(size_t)i * CDIM + lane * 4] = l;
}

// Layer-2 GCN aggregate, PROTEIN rows only (drug h2 rows are dead).
__global__ __launch_bounds__(256) void aggregate2p(const float* __restrict__ tmp2,
                                                   const int* __restrict__ cur_p,
                                                   const int* __restrict__ adj_prot,
                                                   const float* __restrict__ dinv,
                                                   const float* __restrict__ bias,
                                                   unsigned short* __restrict__ h2bf) {
    int w = (blockIdx.x * blockDim.x + threadIdx.x) >> 6;
    int lane = threadIdx.x & 63;
    if (w >= N_PROT) return;
    int i = NUM_DRUGS + w;
    float di = dinv[i];
    float4 a0 = make_float4(0.f, 0.f, 0.f, 0.f);
    float4 a1 = a0, a2 = a0, a3 = a0;
    const int* adj = adj_prot + (size_t)i * ELLP;
    int e = cur_p[i * STRP];
    int idx = 0;
    for (; idx + 4 <= e; idx += 4) {
        int j0 = adj[idx + 0], j1 = adj[idx + 1];
        int j2 = adj[idx + 2], j3 = adj[idx + 3];
        float d0 = dinv[j0], d1 = dinv[j1], d2 = dinv[j2], d3 = dinv[j3];
        float4 v0 = ((const float4*)(tmp2 + (size_t)j0 * CDIM))[lane];
        float4 v1 = ((const float4*)(tmp2 + (size_t)j1 * CDIM))[lane];
        float4 v2 = ((const float4*)(tmp2 + (size_t)j2 * CDIM))[lane];
        float4 v3 = ((const float4*)(tmp2 + (size_t)j3 * CDIM))[lane];
        a0 = f4fma(v0, d0, a0);
        a1 = f4fma(v1, d1, a1);
        a2 = f4fma(v2, d2, a2);
        a3 = f4fma(v3, d3, a3);
    }
    for (; idx < e; idx++) {
        int j = adj[idx];
        a0 = f4fma(((const float4*)(tmp2 + (size_t)j * CDIM))[lane], dinv[j], a0);
    }
    float4 self = ((const float4*)(tmp2 + (size_t)i * CDIM))[lane];
    float4 acc;
    acc.x = (a0.x + a1.x) + (a2.x + a3.x) + self.x * di;
    acc.y = (a0.y + a1.y) + (a2.y + a3.y) + self.y * di;
    acc.z = (a0.z + a1.z) + (a2.z + a3.z) + self.z * di;
    acc.w = (a0.w + a1.w) + (a2.w + a3.w) + self.w * di;
    float4 bv = ((const float4*)bias)[lane];
    ushort4 o;
    o.x = f2bf(fmaxf(fmaf(acc.x, di, bv.x), 0.f));
    o.y = f2bf(fmaxf(fmaf(acc.y, di, bv.y), 0.f));
    o.z = f2bf(fmaxf(fmaf(acc.z, di, bv.z), 0.f));
    o.w = f2bf(fmaxf(fmaf(acc.w, di, bv.w), 0.f));
    *(ushort4*)&h2bf[(size_t)i * CDIM + lane * 4] = o;
}

// scatter-mean pool from bf16 h2 -> split-bf16 graph embeddings
__global__ __launch_bounds__(256) void pool_drugs(const unsigned short* __restrict__ h2bf,
                                                  unsigned short* __restrict__ Ghi,
                                                  unsigned short* __restrict__ Glo,
                                                  const int* __restrict__ cur_d,
                                                  const int* __restrict__ adj_drug) {
    int d = (blockIdx.x * blockDim.x + threadIdx.x) >> 6;
    int lane = threadIdx.x & 63;
    if (d >= NUM_DRUGS) return;
    const int* adj = adj_drug + (size_t)d * ELLD;
    int e = cur_d[d * STRD];
    float4 a0 = make_float4(0.f, 0.f, 0.f, 0.f);
    float4 a1 = a0, a2 = a0, a3 = a0;
    int idx = 0;
    for (; idx + 4 <= e; idx += 4) {
        int j0 = adj[idx + 0], j1 = adj[idx + 1];
        int j2 = adj[idx + 2], j3 = adj[idx + 3];
        float4 v0 = bf4(&h2bf[(size_t)j0 * CDIM + lane * 4]);
        float4 v1 = bf4(&h2bf[(size_t)j1 * CDIM + lane * 4]);
        float4 v2 = bf4(&h2bf[(size_t)j2 * CDIM + lane * 4]);
        float4 v3 = bf4(&h2bf[(size_t)j3 * CDIM + lane * 4]);
        a0.x += v0.x; a0.y += v0.y; a0.z += v0.z; a0.w += v0.w;
        a1.x += v1.x; a1.y += v1.y; a1.z += v1.z; a1.w += v1.w;
        a2.x += v2.x; a2.y += v2.y; a2.z += v2.z; a2.w += v2.w;
        a3.x += v3.x; a3.y += v3.y; a3.z += v3.z; a3.w += v3.w;
    }
    for (; idx < e; idx++) {
        int j = adj[idx];
        float4 v = bf4(&h2bf[(size_t)j * CDIM + lane * 4]);
        a0.x += v.x; a0.y += v.y; a0.z += v.z; a0.w += v.w;
    }
    float4 acc;
    acc.x = (a0.x + a1.x) + (a2.x + a3.x);
    acc.y = (a0.y + a1.y) + (a2.y + a3.y);
    acc.z = (a0.z + a1.z) + (a2.z + a3.z);
    acc.w = (a0.w + a1.w) + (a2.w + a3.w);
    int cnt = e;
    float sc = 1.f / (float)(cnt > 1 ? cnt : 1);
    acc.x *= sc; acc.y *= sc; acc.z *= sc; acc.w *= sc;
    ushort4 h, l;
    split2(acc.x, h.x, l.x); split2(acc.y, h.y, l.y);
    split2(acc.z, h.z, l.z); split2(acc.w, h.w, l.w);
    *(ushort4*)&Ghi[(size_t)d * CDIM + lane * 4] = h;
    *(ushort4*)&Glo[(size_t)d * CDIM + lane * 4] = l;
}

// ---------------------------------------------------------------------------
// MLP epilogue: gather 2 H rows, relu+dot W2, direct store
__global__ __launch_bounds__(256) void mlp_out(const float* __restrict__ H,
                                               const int* __restrict__ ddb,
                                               const int* __restrict__ ecl,
                                               const float* __restrict__ b1,
                                               const float* __restrict__ W2,
                                               const float* __restrict__ b2,
                                               float* __restrict__ outp) {
    int r = (blockIdx.x * blockDim.x + threadIdx.x) >> 6;
    int lane = threadIdx.x & 63;
    if (r >= BATCH) return;
    int c = ecl[r];
    int d0 = ddb[r], d1 = ddb[BATCH + r];
    const float* h0 = H + (size_t)d0 * HN + (size_t)(c * 2) * HID;
    const float* h1 = H + (size_t)d1 * HN + (size_t)(c * 2 + 1) * HID;
    const float* b1e = b1 + (size_t)c * HID;
    const float* w2e = W2 + (size_t)c * HID;
    float s = 0.f;
#pragma unroll
    for (int u = 0; u < 2; u++) {
        int n = u * 256 + lane * 4;
        float4 a = *(const float4*)(h0 + n);
        float4 b = *(const float4*)(h1 + n);
        float4 bb = *(const float4*)(b1e + n);
        float4 ww = *(const float4*)(w2e + n);
        s = fmaf(fmaxf(a.x + b.x + bb.x, 0.f), ww.x, s);
        s = fmaf(fmaxf(a.y + b.y + bb.y, 0.f), ww.y, s);
        s = fmaf(fmaxf(a.z + b.z + bb.z, 0.f), ww.z, s);
        s = fmaf(fmaxf(a.w + b.w + bb.w, 0.f), ww.w, s);
    }
    s += __shfl_xor(s, 1);
    s += __shfl_xor(s, 2);
    s += __shfl_xor(s, 4);
    s += __shfl_xor(s, 8);
    s += __shfl_xor(s, 16);
    s += __shfl_xor(s, 32);
    if (lane == 0) outp[r] = s + b2[c];
}

// ---------------------------------------------------------------------------
extern "C" void kernel_launch(void* const* d_in, const int* in_sizes, int n_in,
                              void* d_out, int out_size, void* d_ws, size_t ws_size,
                              hipStream_t stream) {
    const float* x   = (const float*)d_in[0];
    const int* ei    = (const int*)d_in[1];
    const int* ddb   = (const int*)d_in[2];
    const int* ecl   = (const int*)d_in[3];
    const float* Wg1 = (const float*)d_in[5];
    const float* bg1 = (const float*)d_in[6];
    const float* Wg2 = (const float*)d_in[7];
    const float* bg2 = (const float*)d_in[8];
    const float* W1  = (const float*)d_in[9];
    const float* b1  = (const float*)d_in[10];
    const float* W2  = (const float*)d_in[11];
    const float* b2  = (const float*)d_in[12];
    float* outp = (float*)d_out;

    const size_t NC = (size_t)N_NODES * CDIM;                      // 5.12M elems
    const size_t HBYTES = (size_t)NUM_DRUGS * HN * sizeof(float);  // 67.1 MB
    // Region 0 (inside H extent; all dead before the H GEMM writes H)
    char* r0 = (char*)d_ws;
    float* H              = (float*)d_ws;
    float* tmp            = (float*)r0;
    unsigned short* t1bf  = (unsigned short*)(r0 + 20480000);
    unsigned short* h2bf  = t1bf;
    unsigned short* h1hi  = (unsigned short*)(r0 + 30720000);
    unsigned short* h1lo  = (unsigned short*)(r0 + 40960000);
    unsigned short* xhi   = h1hi;
    unsigned short* xlo   = h1lo;
    char* p = r0 + 51200000;
    auto alloc = [&](size_t bytes) {
        char* r = p;
        p += (bytes + 255) & ~size_t(255);
        return (void*)r;
    };
    float* dinv    = (float*)alloc(sizeof(float) * N_NODES);
    int* cur_d     = (int*)alloc(sizeof(int) * NUM_DRUGS * STRD);
    int* cur_p     = (int*)alloc(sizeof(int) * N_NODES * STRP);
    int* adj_drug  = (int*)alloc(sizeof(int) * NUM_DRUGS * ELLD);
    int* adj_prot  = (int*)alloc(sizeof(int) * (size_t)N_NODES * ELLP);
    // Region 1 (after H extent): buffers the H GEMM reads
    p = (char*)d_ws + ((HBYTES + 255) & ~size_t(255));
    unsigned short* Ghi   = (unsigned short*)alloc(2 * NUM_DRUGS * CDIM);
    unsigned short* Glo   = (unsigned short*)alloc(2 * NUM_DRUGS * CDIM);
    unsigned short* wg1Th = (unsigned short*)alloc(2 * CDIM * CDIM);
    unsigned short* wg1Tl = (unsigned short*)alloc(2 * CDIM * CDIM);
    unsigned short* wg2Th = (unsigned short*)alloc(2 * CDIM * CDIM);
    unsigned short* wg2Tl = (unsigned short*)alloc(2 * CDIM * CDIM);
    unsigned short* W1Th  = (unsigned short*)alloc(2 * (size_t)N_CL * HID * HID);
    unsigned short* W1Tl  = (unsigned short*)alloc(2 * (size_t)N_CL * HID * HID);

    // graph prep: zero cursors -> ELL fill -> dinv  (no count/scan passes)
    zero_counts<<<(N_NODES + 255) / 256, 256, 0, stream>>>(cur_d, cur_p);
    fill_ell<<<(NUM_DPI + 255) / 256, 256, 0, stream>>>(ei, cur_d, adj_drug,
                                                        cur_p, adj_prot);
    calc_dinv<<<(N_NODES + 255) / 256, 256, 0, stream>>>(cur_d, cur_p, dinv);
    // weight/activation splits (coalesced)
    split_mat<<<((int)NC + 255) / 256, 256, 0, stream>>>(x, xhi, xlo, (int)NC);
    transpose_split64<<<dim3(CDIM / 64, CDIM / 64, 1), 256, 0, stream>>>(
        Wg1, wg1Th, wg1Tl, CDIM, CDIM);
    transpose_split64<<<dim3(CDIM / 64, CDIM / 64, 1), 256, 0, stream>>>(
        Wg2, wg2Th, wg2Tl, CDIM, CDIM);
    // W1 [8][512][512] viewed as 16 slabs [256][512] -> W1cat^T [8192][256] split
    transpose_split64<<<dim3(CDIM / 64, HID / 64, 2 * N_CL), 256, 0, stream>>>(
        W1, W1Th, W1Tl, CDIM, HID);
    // GCN layer 1 (GEMM also emits bf16 copy for the drug-side gather)
    gemm_mfma<<<dim3((N_NODES + 127) / 128, CDIM / 128), 256, 0, stream>>>(
        xhi, xlo, wg1Th, wg1Tl, tmp, t1bf, N_NODES, CDIM, CDIM);
    aggregate1<<<(N_NODES * 64 + 255) / 256, 256, 0, stream>>>(
        tmp, t1bf, cur_d, adj_drug, cur_p, adj_prot, dinv, bg1, h1hi, h1lo);
    // GCN layer 2 (protein rows only downstream)
    gemm_mfma<<<dim3((N_NODES + 127) / 128, CDIM / 128), 256, 0, stream>>>(
        h1hi, h1lo, wg2Th, wg2Tl, tmp, nullptr, N_NODES, CDIM, CDIM);
    aggregate2p<<<(N_PROT * 64 + 255) / 256, 256, 0, stream>>>(
        tmp, cur_p, adj_prot, dinv, bg2, h2bf);
    // pool (bf16 gather) -> split graph embeddings
    pool_drugs<<<(NUM_DRUGS * 64 + 255) / 256, 256, 0, stream>>>(h2bf, Ghi, Glo,
                                                                 cur_d, adj_drug);
    // MLP precompute: H[2048, 8192] = G @ W1cat (regular dense GEMM)
    gemm_mfma<<<dim3(NUM_DRUGS / 128, HN / 128), 256, 0, stream>>>(
        Ghi, Glo, W1Th, W1Tl, H, nullptr, NUM_DRUGS, CDIM, HN);
    // epilogue: gather 2 H rows per batch row, relu+dot, direct store
    mlp_out<<<(BATCH * 64) / 256, 256, 0, stream>>>(H, ddb, ecl, b1, W2, b2, outp);
}

// Round 12
// 281.832 us; speedup vs baseline: 1.5815x; 1.0295x over previous
//
#include <hip/hip_runtime.h>
#include <hip/hip_bf16.h>

// Problem constants (fixed by reference)
#define N_NODES 20000
#define NUM_DRUGS 2048
#define N_PROT (N_NODES - NUM_DRUGS)
#define NUM_DPI 200000
#define E2 400000          // 2*NUM_DPI directed edges
#define CDIM 256           // IN_C == EMB == 256
#define HID 512
#define N_CL 8
#define BATCH 16384
#define HN 8192            // H cols = 8 experts x 2 halves x 512

#define STRD 32            // drug counter padding (ints) = 1 line per counter
#define STRP 16            // protein counter padding
#define ELLD 192           // drug ELL stride (mean deg 97.7, +9.5 sigma)
#define ELLP 48            // protein ELL stride (mean deg 11.1, +11 sigma)

typedef __attribute__((ext_vector_type(8))) short short8;   // 8 bf16 (MFMA A/B frag)
typedef __attribute__((ext_vector_type(4))) float floatx4;  // MFMA C/D frag

__device__ inline unsigned short f2bf(float f) {
    unsigned u = __float_as_uint(f);
    u += 0x7fff + ((u >> 16) & 1);   // RNE
    return (unsigned short)(u >> 16);
}
__device__ inline float bf2f(unsigned short h) {
    return __uint_as_float((unsigned)h << 16);
}
__device__ inline void split2(float v, unsigned short& h, unsigned short& l) {
    h = f2bf(v);
    l = f2bf(v - bf2f(h));
}
__device__ inline void gload16(const void* g, void* l) {
    __builtin_amdgcn_global_load_lds(
        (const __attribute__((address_space(1))) void*)g,
        (__attribute__((address_space(3))) void*)l, 16, 0, 0);
}
__device__ inline float4 f4fma(float4 v, float s, float4 a) {
    a.x = fmaf(v.x, s, a.x); a.y = fmaf(v.y, s, a.y);
    a.z = fmaf(v.z, s, a.z); a.w = fmaf(v.w, s, a.w);
    return a;
}
__device__ inline float4 bf4(const unsigned short* p) {
    ushort4 q = *(const ushort4*)p;
    return make_float4(bf2f(q.x), bf2f(q.y), bf2f(q.z), bf2f(q.w));
}

// ---------------------------------------------------------------------------
__global__ void zero_counts(int* cur_d, int* cur_p) {
    int i = blockIdx.x * blockDim.x + threadIdx.x;
    if (i < N_NODES) cur_p[i * STRP] = 0;
    if (i < NUM_DRUGS) cur_d[i * STRD] = 0;
}

// fill both ELL adjacency lists directly (no count/scan passes needed)
__global__ void fill_ell(const int* __restrict__ ei, int* cur_d, int* adj_drug,
                         int* cur_p, int* adj_prot) {
    int e = blockIdx.x * blockDim.x + threadIdx.x;
    if (e >= NUM_DPI) return;
    int d = ei[e];
    int p = ei[E2 + e];
    int posd = atomicAdd(&cur_d[d * STRD], 1);
    int posp = atomicAdd(&cur_p[p * STRP], 1);
    if (posd < ELLD) adj_drug[d * ELLD + posd] = p;   // clamp: never corrupt neighbor
    if (posp < ELLP) adj_prot[(size_t)p * ELLP + posp] = d;
}

// dinv from final cursor values (deg + 1 self-loop)
__global__ void calc_dinv(const int* __restrict__ cur_d, const int* __restrict__ cur_p,
                          float* __restrict__ dinv) {
    int i = blockIdx.x * blockDim.x + threadIdx.x;
    if (i >= N_NODES) return;
    int deg = (i < NUM_DRUGS) ? cur_d[i * STRD] : cur_p[i * STRP];
    dinv[i] = rsqrtf((float)(deg + 1));
}

// ---------------------------------------------------------------------------
__global__ void split_mat(const float* __restrict__ A, unsigned short* __restrict__ hi,
                          unsigned short* __restrict__ lo, int total) {
    int i = blockIdx.x * blockDim.x + threadIdx.x;
    if (i >= total) return;
    unsigned short h, l;
    split2(A[i], h, l);
    hi[i] = h; lo[i] = l;
}

// LDS-tiled transpose+split: W [m][K][N] fp32 -> [m][N][K] split bf16, coalesced
__global__ __launch_bounds__(256) void transpose_split64(const float* __restrict__ W,
                                                         unsigned short* __restrict__ hi,
                                                         unsigned short* __restrict__ lo,
                                                         int K, int N) {
    __shared__ float ld[64 * 65];
    int m = blockIdx.z;
    int k0 = blockIdx.x * 64, n0 = blockIdx.y * 64;
    const float* Wm = W + (size_t)m * K * N;
    int tx = threadIdx.x & 63, ty = threadIdx.x >> 6;
#pragma unroll
    for (int rr = 0; rr < 16; rr++) {
        int kl = rr * 4 + ty;
        ld[tx * 65 + kl] = Wm[(size_t)(k0 + kl) * N + n0 + tx];
    }
    __syncthreads();
    size_t obase = (size_t)m * N * K;
#pragma unroll
    for (int rr = 0; rr < 16; rr++) {
        int nl = rr * 4 + ty;
        float v = ld[nl * 65 + tx];
        unsigned short h, l;
        split2(v, h, l);
        size_t o = obase + (size_t)(n0 + nl) * K + k0 + tx;
        hi[o] = h;
        lo[o] = l;
    }
}

// merged Wg1+Wg2 transpose (both [256][256]); blockIdx.z selects the matrix
__global__ __launch_bounds__(256) void transpose_split_wg(
        const float* __restrict__ Wa, const float* __restrict__ Wb,
        unsigned short* __restrict__ hia, unsigned short* __restrict__ loa,
        unsigned short* __restrict__ hib, unsigned short* __restrict__ lob) {
    __shared__ float ld[64 * 65];
    const float* W = blockIdx.z ? Wb : Wa;
    unsigned short* hi = blockIdx.z ? hib : hia;
    unsigned short* lo = blockIdx.z ? lob : loa;
    int k0 = blockIdx.x * 64, n0 = blockIdx.y * 64;
    int tx = threadIdx.x & 63, ty = threadIdx.x >> 6;
#pragma unroll
    for (int rr = 0; rr < 16; rr++) {
        int kl = rr * 4 + ty;
        ld[tx * 65 + kl] = W[(size_t)(k0 + kl) * CDIM + n0 + tx];
    }
    __syncthreads();
#pragma unroll
    for (int rr = 0; rr < 16; rr++) {
        int nl = rr * 4 + ty;
        float v = ld[nl * 65 + tx];
        unsigned short h, l;
        split2(v, h, l);
        size_t o = (size_t)(n0 + nl) * CDIM + k0 + tx;
        hi[o] = h;
        lo[o] = l;
    }
}

// ---------------------------------------------------------------------------
// split-bf16 MFMA GEMM: C[M,N] = A[M,K] @ B[K,N], B passed as B^T ([N][K]).
// Row-major XOR-swizzled LDS; fp32 (C) and/or bf16 (Cbf) outputs, each optional.
__global__ __launch_bounds__(256) void gemm_mfma(
        const unsigned short* __restrict__ Ahi, const unsigned short* __restrict__ Alo,
        const unsigned short* __restrict__ BThi, const unsigned short* __restrict__ BTlo,
        float* __restrict__ C, unsigned short* __restrict__ Cbf,
        int M, int K, int N) {
    __shared__ unsigned short sAh[4096], sAl[4096], sBh[4096], sBl[4096];
    int t = threadIdx.x;
    int wv = t >> 6, lane = t & 63, quad = lane >> 4, l15 = lane & 15;
    int m0 = blockIdx.x * 128, n0 = blockIdx.y * 128;
    int m0w = (wv >> 1) * 64, n0w = (wv & 1) * 64;
    floatx4 zero = {0.f, 0.f, 0.f, 0.f};
    floatx4 acc[4][4];
#pragma unroll
    for (int i = 0; i < 4; i++)
#pragma unroll
        for (int j = 0; j < 4; j++) acc[i][j] = zero;

    for (int kk = 0; kk < K; kk += 32) {
#pragma unroll
        for (int c = 0; c < 2; c++) {
            int s = t + c * 256;                 // slot in [0,512)
            int row = s >> 2, pos = s & 3;
            int ch = pos ^ ((row >> 1) & 3);     // XOR-swizzled chunk
            int arow = m0 + row; if (arow > M - 1) arow = M - 1;
            int brow = n0 + row; if (brow > N - 1) brow = N - 1;
            size_t aoff = (size_t)arow * K + kk + ch * 8;
            size_t boff = (size_t)brow * K + kk + ch * 8;
            gload16(Ahi + aoff, &sAh[s * 8]);
            gload16(Alo + aoff, &sAl[s * 8]);
            gload16(BThi + boff, &sBh[s * 8]);
            gload16(BTlo + boff, &sBl[s * 8]);
        }
        __syncthreads();
        short8 ah[4], al[4], bh[4], bl[4];
        int posq = quad ^ ((l15 >> 1) & 3);
#pragma unroll
        for (int i = 0; i < 4; i++) {
            int sl = (m0w + i * 16 + l15) * 4 + posq;
            ah[i] = *(const short8*)&sAh[sl * 8];
            al[i] = *(const short8*)&sAl[sl * 8];
        }
#pragma unroll
        for (int j = 0; j < 4; j++) {
            int sl = (n0w + j * 16 + l15) * 4 + posq;
            bh[j] = *(const short8*)&sBh[sl * 8];
            bl[j] = *(const short8*)&sBl[sl * 8];
        }
#pragma unroll
        for (int i = 0; i < 4; i++)
#pragma unroll
            for (int j = 0; j < 4; j++) {
                acc[i][j] = __builtin_amdgcn_mfma_f32_16x16x32_bf16(ah[i], bh[j], acc[i][j], 0, 0, 0);
                acc[i][j] = __builtin_amdgcn_mfma_f32_16x16x32_bf16(ah[i], bl[j], acc[i][j], 0, 0, 0);
                acc[i][j] = __builtin_amdgcn_mfma_f32_16x16x32_bf16(al[i], bh[j], acc[i][j], 0, 0, 0);
            }
        __syncthreads();
    }
#pragma unroll
    for (int i = 0; i < 4; i++) {
        int gr = m0 + m0w + i * 16 + quad * 4;
#pragma unroll
        for (int r = 0; r < 4; r++) {
            if (gr + r < M) {
#pragma unroll
                for (int j = 0; j < 4; j++) {
                    size_t o = (size_t)(gr + r) * N + n0 + n0w + j * 16 + l15;
                    float v = acc[i][j][r];
                    if (C) C[o] = v;
                    if (Cbf) Cbf[o] = f2bf(v);
                }
            }
        }
    }
}

// ---------------------------------------------------------------------------
// Layer-1 GCN aggregate over ELL lists. Drug destinations gather protein rows
// bf16 (halved traffic); protein destinations gather drug rows fp32 (L2-res).
__global__ __launch_bounds__(256) void aggregate1(const float* __restrict__ tmp,
                                                  const unsigned short* __restrict__ tmpbf,
                                                  const int* __restrict__ cur_d,
                                                  const int* __restrict__ adj_drug,
                                                  const int* __restrict__ cur_p,
                                                  const int* __restrict__ adj_prot,
                                                  const float* __restrict__ dinv,
                                                  const float* __restrict__ bias,
                                                  unsigned short* __restrict__ outhi,
                                                  unsigned short* __restrict__ outlo) {
    int i = (blockIdx.x * blockDim.x + threadIdx.x) >> 6;
    int lane = threadIdx.x & 63;
    if (i >= N_NODES) return;
    float di = dinv[i];
    float4 a0 = make_float4(0.f, 0.f, 0.f, 0.f);
    float4 a1 = a0, a2 = a0, a3 = a0;
    if (i < NUM_DRUGS) {
        const int* adj = adj_drug + (size_t)i * ELLD;
        int e = cur_d[i * STRD];
        int idx = 0;
        for (; idx + 4 <= e; idx += 4) {
            int j0 = adj[idx + 0], j1 = adj[idx + 1];
            int j2 = adj[idx + 2], j3 = adj[idx + 3];
            float d0 = dinv[j0], d1 = dinv[j1], d2 = dinv[j2], d3 = dinv[j3];
            float4 v0 = bf4(&tmpbf[(size_t)j0 * CDIM + lane * 4]);
            float4 v1 = bf4(&tmpbf[(size_t)j1 * CDIM + lane * 4]);
            float4 v2 = bf4(&tmpbf[(size_t)j2 * CDIM + lane * 4]);
            float4 v3 = bf4(&tmpbf[(size_t)j3 * CDIM + lane * 4]);
            a0 = f4fma(v0, d0, a0);
            a1 = f4fma(v1, d1, a1);
            a2 = f4fma(v2, d2, a2);
            a3 = f4fma(v3, d3, a3);
        }
        for (; idx < e; idx++) {
            int j = adj[idx];
            a0 = f4fma(bf4(&tmpbf[(size_t)j * CDIM + lane * 4]), dinv[j], a0);
        }
    } else {
        const int* adj = adj_prot + (size_t)i * ELLP;
        int e = cur_p[i * STRP];
        int idx = 0;
        for (; idx + 4 <= e; idx += 4) {
            int j0 = adj[idx + 0], j1 = adj[idx + 1];
            int j2 = adj[idx + 2], j3 = adj[idx + 3];
            float d0 = dinv[j0], d1 = dinv[j1], d2 = dinv[j2], d3 = dinv[j3];
            float4 v0 = ((const float4*)(tmp + (size_t)j0 * CDIM))[lane];
            float4 v1 = ((const float4*)(tmp + (size_t)j1 * CDIM))[lane];
            float4 v2 = ((const float4*)(tmp + (size_t)j2 * CDIM))[lane];
            float4 v3 = ((const float4*)(tmp + (size_t)j3 * CDIM))[lane];
            a0 = f4fma(v0, d0, a0);
            a1 = f4fma(v1, d1, a1);
            a2 = f4fma(v2, d2, a2);
            a3 = f4fma(v3, d3, a3);
        }
        for (; idx < e; idx++) {
            int j = adj[idx];
            a0 = f4fma(((const float4*)(tmp + (size_t)j * CDIM))[lane], dinv[j], a0);
        }
    }
    float4 self = ((const float4*)(tmp + (size_t)i * CDIM))[lane];
    float4 acc;
    acc.x = (a0.x + a1.x) + (a2.x + a3.x) + self.x * di;
    acc.y = (a0.y + a1.y) + (a2.y + a3.y) + self.y * di;
    acc.z = (a0.z + a1.z) + (a2.z + a3.z) + self.z * di;
    acc.w = (a0.w + a1.w) + (a2.w + a3.w) + self.w * di;
    float4 bv = ((const float4*)bias)[lane];
    float4 r;
    r.x = fmaxf(fmaf(acc.x, di, bv.x), 0.f);
    r.y = fmaxf(fmaf(acc.y, di, bv.y), 0.f);
    r.z = fmaxf(fmaf(acc.z, di, bv.z), 0.f);
    r.w = fmaxf(fmaf(acc.w, di, bv.w), 0.f);
    ushort4 h, l;
    split2(r.x, h.x, l.x); split2(r.y, h.y, l.y);
    split2(r.z, h.z, l.z); split2(r.w, h.w, l.w);
    *(ushort4*)&outhi[(size_t)i * CDIM + lane * 4] = h;
    *(ushort4*)&outlo[(size_t)i * CDIM + lane * 4] = l;
}

// Layer-2 GCN aggregate, PROTEIN rows only (drug h2 rows are dead).
__global__ __launch_bounds__(256) void aggregate2p(const float* __restrict__ tmp2,
                                                   const int* __restrict__ cur_p,
                                                   const int* __restrict__ adj_prot,
                                                   const float* __restrict__ dinv,
                                                   const float* __restrict__ bias,
                                                   unsigned short* __restrict__ h2bf) {
    int w = (blockIdx.x * blockDim.x + threadIdx.x) >> 6;
    int lane = threadIdx.x & 63;
    if (w >= N_PROT) return;
    int i = NUM_DRUGS + w;
    float di = dinv[i];
    float4 a0 = make_float4(0.f, 0.f, 0.f, 0.f);
    float4 a1 = a0, a2 = a0, a3 = a0;
    const int* adj = adj_prot + (size_t)i * ELLP;
    int e = cur_p[i * STRP];
    int idx = 0;
    for (; idx + 4 <= e; idx += 4) {
        int j0 = adj[idx + 0], j1 = adj[idx + 1];
        int j2 = adj[idx + 2], j3 = adj[idx + 3];
        float d0 = dinv[j0], d1 = dinv[j1], d2 = dinv[j2], d3 = dinv[j3];
        float4 v0 = ((const float4*)(tmp2 + (size_t)j0 * CDIM))[lane];
        float4 v1 = ((const float4*)(tmp2 + (size_t)j1 * CDIM))[lane];
        float4 v2 = ((const float4*)(tmp2 + (size_t)j2 * CDIM))[lane];
        float4 v3 = ((const float4*)(tmp2 + (size_t)j3 * CDIM))[lane];
        a0 = f4fma(v0, d0, a0);
        a1 = f4fma(v1, d1, a1);
        a2 = f4fma(v2, d2, a2);
        a3 = f4fma(v3, d3, a3);
    }
    for (; idx < e; idx++) {
        int j = adj[idx];
        a0 = f4fma(((const float4*)(tmp2 + (size_t)j * CDIM))[lane], dinv[j], a0);
    }
    float4 self = ((const float4*)(tmp2 + (size_t)i * CDIM))[lane];
    float4 acc;
    acc.x = (a0.x + a1.x) + (a2.x + a3.x) + self.x * di;
    acc.y = (a0.y + a1.y) + (a2.y + a3.y) + self.y * di;
    acc.z = (a0.z + a1.z) + (a2.z + a3.z) + self.z * di;
    acc.w = (a0.w + a1.w) + (a2.w + a3.w) + self.w * di;
    float4 bv = ((const float4*)bias)[lane];
    ushort4 o;
    o.x = f2bf(fmaxf(fmaf(acc.x, di, bv.x), 0.f));
    o.y = f2bf(fmaxf(fmaf(acc.y, di, bv.y), 0.f));
    o.z = f2bf(fmaxf(fmaf(acc.z, di, bv.z), 0.f));
    o.w = f2bf(fmaxf(fmaf(acc.w, di, bv.w), 0.f));
    *(ushort4*)&h2bf[(size_t)i * CDIM + lane * 4] = o;
}

// scatter-mean pool from bf16 h2 -> split-bf16 graph embeddings
__global__ __launch_bounds__(256) void pool_drugs(const unsigned short* __restrict__ h2bf,
                                                  unsigned short* __restrict__ Ghi,
                                                  unsigned short* __restrict__ Glo,
                                                  const int* __restrict__ cur_d,
                                                  const int* __restrict__ adj_drug) {
    int d = (blockIdx.x * blockDim.x + threadIdx.x) >> 6;
    int lane = threadIdx.x & 63;
    if (d >= NUM_DRUGS) return;
    const int* adj = adj_drug + (size_t)d * ELLD;
    int e = cur_d[d * STRD];
    float4 a0 = make_float4(0.f, 0.f, 0.f, 0.f);
    float4 a1 = a0, a2 = a0, a3 = a0;
    int idx = 0;
    for (; idx + 4 <= e; idx += 4) {
        int j0 = adj[idx + 0], j1 = adj[idx + 1];
        int j2 = adj[idx + 2], j3 = adj[idx + 3];
        float4 v0 = bf4(&h2bf[(size_t)j0 * CDIM + lane * 4]);
        float4 v1 = bf4(&h2bf[(size_t)j1 * CDIM + lane * 4]);
        float4 v2 = bf4(&h2bf[(size_t)j2 * CDIM + lane * 4]);
        float4 v3 = bf4(&h2bf[(size_t)j3 * CDIM + lane * 4]);
        a0.x += v0.x; a0.y += v0.y; a0.z += v0.z; a0.w += v0.w;
        a1.x += v1.x; a1.y += v1.y; a1.z += v1.z; a1.w += v1.w;
        a2.x += v2.x; a2.y += v2.y; a2.z += v2.z; a2.w += v2.w;
        a3.x += v3.x; a3.y += v3.y; a3.z += v3.z; a3.w += v3.w;
    }
    for (; idx < e; idx++) {
        int j = adj[idx];
        float4 v = bf4(&h2bf[(size_t)j * CDIM + lane * 4]);
        a0.x += v.x; a0.y += v.y; a0.z += v.z; a0.w += v.w;
    }
    float4 acc;
    acc.x = (a0.x + a1.x) + (a2.x + a3.x);
    acc.y = (a0.y + a1.y) + (a2.y + a3.y);
    acc.z = (a0.z + a1.z) + (a2.z + a3.z);
    acc.w = (a0.w + a1.w) + (a2.w + a3.w);
    int cnt = e;
    float sc = 1.f / (float)(cnt > 1 ? cnt : 1);
    acc.x *= sc; acc.y *= sc; acc.z *= sc; acc.w *= sc;
    ushort4 h, l;
    split2(acc.x, h.x, l.x); split2(acc.y, h.y, l.y);
    split2(acc.z, h.z, l.z); split2(acc.w, h.w, l.w);
    *(ushort4*)&Ghi[(size_t)d * CDIM + lane * 4] = h;
    *(ushort4*)&Glo[(size_t)d * CDIM + lane * 4] = l;
}

// ---------------------------------------------------------------------------
// MLP epilogue: out[r] = sum_n relu(H[d0][2c*512+n] + H[d1][(2c+1)*512+n]
//                                   + b1[c][n]) * W2[c][n] + b2[c]
// H in bf16; one wave per row; lane covers 8 cols -> single pass, 16B loads.
__global__ __launch_bounds__(256) void mlp_out(const unsigned short* __restrict__ Hbf,
                                               const int* __restrict__ ddb,
                                               const int* __restrict__ ecl,
                                               const float* __restrict__ b1,
                                               const float* __restrict__ W2,
                                               const float* __restrict__ b2,
                                               float* __restrict__ outp) {
    int r = (blockIdx.x * blockDim.x + threadIdx.x) >> 6;
    int lane = threadIdx.x & 63;
    if (r >= BATCH) return;
    int c = ecl[r];
    int d0 = ddb[r], d1 = ddb[BATCH + r];
    int n = lane * 8;
    const unsigned short* h0 = Hbf + (size_t)d0 * HN + (size_t)(c * 2) * HID + n;
    const unsigned short* h1 = Hbf + (size_t)d1 * HN + (size_t)(c * 2 + 1) * HID + n;
    const float* b1e = b1 + (size_t)c * HID + n;
    const float* w2e = W2 + (size_t)c * HID + n;
    short8 a8 = *(const short8*)h0;
    short8 b8 = *(const short8*)h1;
    float4 bb0 = *(const float4*)(b1e);
    float4 bb1 = *(const float4*)(b1e + 4);
    float4 w0 = *(const float4*)(w2e);
    float4 w1 = *(const float4*)(w2e + 4);
    float s = 0.f;
    float h;
    h = bf2f((unsigned short)a8[0]) + bf2f((unsigned short)b8[0]) + bb0.x;
    s = fmaf(fmaxf(h, 0.f), w0.x, s);
    h = bf2f((unsigned short)a8[1]) + bf2f((unsigned short)b8[1]) + bb0.y;
    s = fmaf(fmaxf(h, 0.f), w0.y, s);
    h = bf2f((unsigned short)a8[2]) + bf2f((unsigned short)b8[2]) + bb0.z;
    s = fmaf(fmaxf(h, 0.f), w0.z, s);
    h = bf2f((unsigned short)a8[3]) + bf2f((unsigned short)b8[3]) + bb0.w;
    s = fmaf(fmaxf(h, 0.f), w0.w, s);
    h = bf2f((unsigned short)a8[4]) + bf2f((unsigned short)b8[4]) + bb1.x;
    s = fmaf(fmaxf(h, 0.f), w1.x, s);
    h = bf2f((unsigned short)a8[5]) + bf2f((unsigned short)b8[5]) + bb1.y;
    s = fmaf(fmaxf(h, 0.f), w1.y, s);
    h = bf2f((unsigned short)a8[6]) + bf2f((unsigned short)b8[6]) + bb1.z;
    s = fmaf(fmaxf(h, 0.f), w1.z, s);
    h = bf2f((unsigned short)a8[7]) + bf2f((unsigned short)b8[7]) + bb1.w;
    s = fmaf(fmaxf(h, 0.f), w1.w, s);
    s += __shfl_xor(s, 1);
    s += __shfl_xor(s, 2);
    s += __shfl_xor(s, 4);
    s += __shfl_xor(s, 8);
    s += __shfl_xor(s, 16);
    s += __shfl_xor(s, 32);
    if (lane == 0) outp[r] = s + b2[c];
}

// ---------------------------------------------------------------------------
extern "C" void kernel_launch(void* const* d_in, const int* in_sizes, int n_in,
                              void* d_out, int out_size, void* d_ws, size_t ws_size,
                              hipStream_t stream) {
    const float* x   = (const float*)d_in[0];
    const int* ei    = (const int*)d_in[1];
    const int* ddb   = (const int*)d_in[2];
    const int* ecl   = (const int*)d_in[3];
    const float* Wg1 = (const float*)d_in[5];
    const float* bg1 = (const float*)d_in[6];
    const float* Wg2 = (const float*)d_in[7];
    const float* bg2 = (const float*)d_in[8];
    const float* W1  = (const float*)d_in[9];
    const float* b1  = (const float*)d_in[10];
    const float* W2  = (const float*)d_in[11];
    const float* b2  = (const float*)d_in[12];
    float* outp = (float*)d_out;

    const size_t NC = (size_t)N_NODES * CDIM;                      // 5.12M elems
    const size_t HRES = (size_t)NUM_DRUGS * HN * sizeof(float);    // 67.1 MB reserved
    // Region 0 (inside reserved extent; all dead before the H GEMM writes Hbf):
    // Hbf (bf16, 33.6 MB) overlaps tmp/t1bf/h1 — all dead at H-GEMM time.
    char* r0 = (char*)d_ws;
    unsigned short* Hbf   = (unsigned short*)d_ws;
    float* tmp            = (float*)r0;
    unsigned short* t1bf  = (unsigned short*)(r0 + 20480000);
    unsigned short* h2bf  = t1bf;
    unsigned short* h1hi  = (unsigned short*)(r0 + 30720000);
    unsigned short* h1lo  = (unsigned short*)(r0 + 40960000);
    unsigned short* xhi   = h1hi;
    unsigned short* xlo   = h1lo;
    char* p = r0 + 51200000;
    auto alloc = [&](size_t bytes) {
        char* r = p;
        p += (bytes + 255) & ~size_t(255);
        return (void*)r;
    };
    float* dinv    = (float*)alloc(sizeof(float) * N_NODES);
    int* cur_d     = (int*)alloc(sizeof(int) * NUM_DRUGS * STRD);
    int* cur_p     = (int*)alloc(sizeof(int) * N_NODES * STRP);
    int* adj_drug  = (int*)alloc(sizeof(int) * NUM_DRUGS * ELLD);
    int* adj_prot  = (int*)alloc(sizeof(int) * (size_t)N_NODES * ELLP);
    // Region 1 (after reserved extent): buffers the H GEMM reads
    p = (char*)d_ws + ((HRES + 255) & ~size_t(255));
    unsigned short* Ghi   = (unsigned short*)alloc(2 * NUM_DRUGS * CDIM);
    unsigned short* Glo   = (unsigned short*)alloc(2 * NUM_DRUGS * CDIM);
    unsigned short* wg1Th = (unsigned short*)alloc(2 * CDIM * CDIM);
    unsigned short* wg1Tl = (unsigned short*)alloc(2 * CDIM * CDIM);
    unsigned short* wg2Th = (unsigned short*)alloc(2 * CDIM * CDIM);
    unsigned short* wg2Tl = (unsigned short*)alloc(2 * CDIM * CDIM);
    unsigned short* W1Th  = (unsigned short*)alloc(2 * (size_t)N_CL * HID * HID);
    unsigned short* W1Tl  = (unsigned short*)alloc(2 * (size_t)N_CL * HID * HID);

    // graph prep: zero cursors -> ELL fill -> dinv  (no count/scan passes)
    zero_counts<<<(N_NODES + 255) / 256, 256, 0, stream>>>(cur_d, cur_p);
    fill_ell<<<(NUM_DPI + 255) / 256, 256, 0, stream>>>(ei, cur_d, adj_drug,
                                                        cur_p, adj_prot);
    calc_dinv<<<(N_NODES + 255) / 256, 256, 0, stream>>>(cur_d, cur_p, dinv);
    // weight/activation splits (coalesced)
    split_mat<<<((int)NC + 255) / 256, 256, 0, stream>>>(x, xhi, xlo, (int)NC);
    transpose_split_wg<<<dim3(CDIM / 64, CDIM / 64, 2), 256, 0, stream>>>(
        Wg1, Wg2, wg1Th, wg1Tl, wg2Th, wg2Tl);
    // W1 [8][512][512] viewed as 16 slabs [256][512] -> W1cat^T [8192][256] split
    transpose_split64<<<dim3(CDIM / 64, HID / 64, 2 * N_CL), 256, 0, stream>>>(
        W1, W1Th, W1Tl, CDIM, HID);
    // GCN layer 1 (GEMM also emits bf16 copy for the drug-side gather)
    gemm_mfma<<<dim3((N_NODES + 127) / 128, CDIM / 128), 256, 0, stream>>>(
        xhi, xlo, wg1Th, wg1Tl, tmp, t1bf, N_NODES, CDIM, CDIM);
    aggregate1<<<(N_NODES * 64 + 255) / 256, 256, 0, stream>>>(
        tmp, t1bf, cur_d, adj_drug, cur_p, adj_prot, dinv, bg1, h1hi, h1lo);
    // GCN layer 2 (protein rows only downstream)
    gemm_mfma<<<dim3((N_NODES + 127) / 128, CDIM / 128), 256, 0, stream>>>(
        h1hi, h1lo, wg2Th, wg2Tl, tmp, nullptr, N_NODES, CDIM, CDIM);
    aggregate2p<<<(N_PROT * 64 + 255) / 256, 256, 0, stream>>>(
        tmp, cur_p, adj_prot, dinv, bg2, h2bf);
    // pool (bf16 gather) -> split graph embeddings
    pool_drugs<<<(NUM_DRUGS * 64 + 255) / 256, 256, 0, stream>>>(h2bf, Ghi, Glo,
                                                                 cur_d, adj_drug);
    // MLP precompute: Hbf[2048, 8192] (bf16) = G @ W1cat (dense GEMM)
    gemm_mfma<<<dim3(NUM_DRUGS / 128, HN / 128), 256, 0, stream>>>(
        Ghi, Glo, W1Th, W1Tl, nullptr, Hbf, NUM_DRUGS, CDIM, HN);
    // epilogue: gather 2 Hbf rows per batch row, relu+dot, direct store
    mlp_out<<<(BATCH * 64) / 256, 256, 0, stream>>>(Hbf, ddb, ecl, b1, W2, b2, outp);
}